// Round 3
// baseline (26488.632 us; speedup 1.0000x reference)
//
#include <hip/hip_runtime.h>
#include <hip/hip_cooperative_groups.h>
#include <math.h>

namespace cg = cooperative_groups;

#define NB 128
#define TT 128
#define HD 1024
#define FH 4096

typedef __attribute__((ext_vector_type(8))) short short8v;
typedef __attribute__((ext_vector_type(4))) float float4v;

__device__ __forceinline__ ushort f2b(float f) {
    union { float f; unsigned u; } v; v.f = f;
    unsigned r = (v.u + 0x7fffu + ((v.u >> 16) & 1u)) >> 16;
    return (ushort)r;
}

// ---------------------------------------------------------------------------
// x fp32 -> bf16 (layout stays [N][T][D])
__global__ __launch_bounds__(256) void cvt_x(const float* __restrict__ x,
                                             ushort* __restrict__ xb) {
    size_t i = (size_t)blockIdx.x * 256 + threadIdx.x;
    const float4* p = (const float4*)x + i * 2;
    float4 va = p[0], vb = p[1];
    union { ushort u[8]; uint4 v; } o;
    o.u[0] = f2b(va.x); o.u[1] = f2b(va.y); o.u[2] = f2b(va.z); o.u[3] = f2b(va.w);
    o.u[4] = f2b(vb.x); o.u[5] = f2b(vb.y); o.u[6] = f2b(vb.z); o.u[7] = f2b(vb.w);
    ((uint4*)xb)[i] = o.v;
}

// ---------------------------------------------------------------------------
// GEMM phase: block owns WT rows [n0, n0+128) x K [kq*384, kq*384+384) in LDS.
// 8 waves: mg = w>>1 (32 M-rows each), ng = w&1 (64 N-cols each).
// A-frags straight from global (16B contiguous-K per lane), B-frags from LDS.
__device__ __forceinline__ void gemmphase(
    const ushort* __restrict__ xb_t,    // + n*131072 + k   (k < 1024)
    const ushort* __restrict__ hattn,   // [128][2048]      (k >= 1024)
    const ushort* Bsl,                  // [128][384] swizzled
    float* __restrict__ a_part,         // [8][128][4096]
    int n0, int kq, int tid)
{
    const int w  = tid >> 6, l = tid & 63;
    const int mg = w >> 1,  ng = w & 1;
    const int lr = l & 15,  g  = l >> 4;
    const int bm = mg * 32;

    float4v acc[2][4];
#pragma unroll
    for (int i = 0; i < 2; ++i)
#pragma unroll
        for (int j = 0; j < 4; ++j) acc[i][j] = (float4v){0.f, 0.f, 0.f, 0.f};

    // per-lane invariant bases
    const ushort* xA0 = xb_t  + (size_t)(bm + lr)      * (TT * HD) + g * 8;
    const ushort* xA1 = xb_t  + (size_t)(bm + 16 + lr) * (TT * HD) + g * 8;
    const ushort* hA0 = hattn + (size_t)(bm + lr)      * 2048      + g * 8;
    const ushort* hA1 = hattn + (size_t)(bm + 16 + lr) * 2048      + g * 8;
    int rowb[4];
#pragma unroll
    for (int bn = 0; bn < 4; ++bn) rowb[bn] = (ng * 64 + bn * 16 + lr) * 384;

    const int kb = kq * 384;
#pragma unroll
    for (int s = 0; s < 12; ++s) {
        const int k0 = kb + s * 32;
        short8v a0, a1;
        if (k0 < 1024) {
            a0 = *(const short8v*)(xA0 + k0);
            a1 = *(const short8v*)(xA1 + k0);
        } else {
            a0 = *(const short8v*)(hA0 + (k0 - 1024));
            a1 = *(const short8v*)(hA1 + (k0 - 1024));
        }
        const int cs = (s * 4 + g) ^ (lr & 7);   // swizzled 16B-chunk slot
#pragma unroll
        for (int bn = 0; bn < 4; ++bn) {
            short8v bf = *(const short8v*)&Bsl[rowb[bn] + cs * 8];
            acc[0][bn] = __builtin_amdgcn_mfma_f32_16x16x32_bf16(a0, bf, acc[0][bn], 0, 0, 0);
            acc[1][bn] = __builtin_amdgcn_mfma_f32_16x16x32_bf16(a1, bf, acc[1][bn], 0, 0, 0);
        }
    }

    float* dst = a_part + (size_t)kq * (NB * FH);
#pragma unroll
    for (int ar = 0; ar < 2; ++ar)
#pragma unroll
        for (int bn = 0; bn < 4; ++bn) {
            const int col  = n0 + ng * 64 + bn * 16 + lr;
            const int mrow = bm + ar * 16 + g * 4;
#pragma unroll
            for (int j = 0; j < 4; ++j)
                dst[(size_t)(mrow + j) * FH + col] = acc[ar][bn][j];
        }
}

// ---------------------------------------------------------------------------
// Fused phase (blocks 0..127, n = bid): gates+cell (t>=0) or meanpool init
// (t<0), then attention for the next step. 512 threads, 2 h-values each.
__device__ __forceinline__ void fusedphase(
    int t, int n, int tid,
    const float* __restrict__ a_part, const float* __restrict__ bias,
    const float* __restrict__ A, float* __restrict__ cbuf,
    ushort* __restrict__ hattn, float* __restrict__ out,
    float (*red)[16])
{
    float p[16];
#pragma unroll
    for (int k = 0; k < 16; ++k) p[k] = 0.f;
    float Areg[2][16];

#pragma unroll
    for (int u = 0; u < 2; ++u) {
        const int h = tid + u * 512;
        const size_t idx = (size_t)n * HD + h;
        const float4* a4 = (const float4*)(A + idx * 16);
#pragma unroll
        for (int q = 0; q < 4; ++q) {
            float4 v = a4[q];
            Areg[u][q * 4 + 0] = v.x; Areg[u][q * 4 + 1] = v.y;
            Areg[u][q * 4 + 2] = v.z; Areg[u][q * 4 + 3] = v.w;
        }
        float hv;
        if (t < 0) {
            float s = 0.f;
#pragma unroll
            for (int k = 0; k < 16; ++k) s += Areg[u][k];
            hv = s * 0.0625f;
            cbuf[idx] = hv;
        } else {
            float ai = bias[h], af = bias[1024 + h], ao = bias[2048 + h], ag = bias[3072 + h];
#pragma unroll
            for (int ks = 0; ks < 8; ++ks) {
                const float* ap = a_part + ((size_t)ks * NB + n) * FH + h;
                ai += ap[0]; af += ap[1024]; ao += ap[2048]; ag += ap[3072];
            }
            float si = 1.f / (1.f + __expf(-ai));
            float sf = 1.f / (1.f + __expf(-af));
            float so = 1.f / (1.f + __expf(-ao));
            float tg = tanhf(ag);
            float cn = sf * cbuf[idx] + si * tg;
            hv = so * tanhf(cn);
            cbuf[idx] = cn;
            out[(size_t)n * (TT * HD) + (size_t)t * HD + h] = hv;
        }
        hattn[(size_t)n * 2048 + h] = f2b(hv);
#pragma unroll
        for (int k = 0; k < 16; ++k) p[k] += hv * Areg[u][k];
    }

    // reduce p[16] over 512 threads: wave shfl + LDS cross-wave
#pragma unroll
    for (int k = 0; k < 16; ++k) {
        float v = p[k];
        v += __shfl_xor(v, 32); v += __shfl_xor(v, 16); v += __shfl_xor(v, 8);
        v += __shfl_xor(v, 4);  v += __shfl_xor(v, 2);  v += __shfl_xor(v, 1);
        p[k] = v;
    }
    const int wv = tid >> 6;
    if ((tid & 63) == 0) {
#pragma unroll
        for (int k = 0; k < 16; ++k) red[wv][k] = p[k];
    }
    __syncthreads();

    float qk[16], mx = -1e30f;
#pragma unroll
    for (int k = 0; k < 16; ++k) {
        float s2 = red[0][k] + red[1][k] + red[2][k] + red[3][k]
                 + red[4][k] + red[5][k] + red[6][k] + red[7][k];
        qk[k] = s2 * 0.03125f;            // 1/sqrt(1024)
        mx = fmaxf(mx, qk[k]);
    }
    float sum = 0.f;
#pragma unroll
    for (int k = 0; k < 16; ++k) { qk[k] = __expf(qk[k] - mx); sum += qk[k]; }
    const float inv = 1.f / sum;
#pragma unroll
    for (int u = 0; u < 2; ++u) {
        float av = 0.f;
#pragma unroll
        for (int k = 0; k < 16; ++k) av += qk[k] * Areg[u][k];
        hattn[(size_t)n * 2048 + 1024 + tid + u * 512] = f2b(av * inv);
    }
}

// ---------------------------------------------------------------------------
__global__ __launch_bounds__(512) void persist(
    const ushort* __restrict__ xb,      // [N][T][D] bf16
    ushort* __restrict__ hattn,         // [N][2048] bf16 (h | attn)
    const float* __restrict__ A,        // [N][1024][16]
    const float* __restrict__ Wx, const float* __restrict__ Wh,
    const float* __restrict__ Wattn,
    const float* __restrict__ bias,
    float* __restrict__ cbuf,           // [N][1024]
    float* __restrict__ a_part,         // [8][128][4096]
    float* __restrict__ out)            // [N][T][H]
{
    cg::grid_group grid = cg::this_grid();
    __shared__ ushort Bsl[128 * 384];   // 96 KB resident W^T slice
    __shared__ float red[8][16];

    const int bid = blockIdx.x;
    const int tid = threadIdx.x;
    const int n0 = (bid >> 3) * 128;
    const int kq = bid & 7;

    // ---- prologue: transpose+convert this block's W slice into LDS ----
    {
        const int row   = tid >> 2;            // 0..127 (N within slice)
        const int cbase = (tid & 3) * 12;      // 16B-chunk index base (48/row)
        for (int i = 0; i < 12; ++i) {
            const int c  = cbase + i;
            const int kg = kq * 384 + c * 8;
            const float* Wsrc; int kl;
            if (kg < 1024)      { Wsrc = Wx;    kl = kg; }
            else if (kg < 2048) { Wsrc = Wh;    kl = kg - 1024; }
            else                { Wsrc = Wattn; kl = kg - 2048; }
            union { ushort u[8]; uint4 v; } t8;
#pragma unroll
            for (int j = 0; j < 8; ++j)
                t8.u[j] = f2b(Wsrc[(size_t)(kl + j) * FH + n0 + row]);
            const int cs = c ^ (row & 7);
            *(uint4*)&Bsl[row * 384 + cs * 8] = t8.v;
        }
    }

    // ---- h0 = c0 = meanpool(A); attn0 ----
    if (bid < NB)
        fusedphase(-1, bid, tid, a_part, bias, A, cbuf, hattn, out, red);
    __threadfence();
    grid.sync();

    for (int t = 0; t < TT; ++t) {
        gemmphase(xb + (size_t)t * HD, hattn, Bsl, a_part, n0, kq, tid);
        __threadfence();
        grid.sync();
        if (bid < NB)
            fusedphase(t, bid, tid, a_part, bias, A, cbuf, hattn, out, red);
        __threadfence();
        grid.sync();
    }
}

// ---------------------------------------------------------------------------
extern "C" void kernel_launch(void* const* d_in, const int* in_sizes, int n_in,
                              void* d_out, int out_size, void* d_ws, size_t ws_size,
                              hipStream_t stream) {
    const float* x     = (const float*)d_in[0];
    const float* A     = (const float*)d_in[1];
    const float* Wx    = (const float*)d_in[2];
    const float* Wh    = (const float*)d_in[3];
    const float* Wattn = (const float*)d_in[4];
    const float* b     = (const float*)d_in[5];
    float* out = (float*)d_out;

    ushort* xb    = (ushort*)d_ws;                        // 33.55 MB
    ushort* hattn = xb + (size_t)NB * TT * HD;            // 0.5 MB
    float*  c_buf = (float*)(hattn + (size_t)NB * 2048);  // 0.5 MB
    float*  a_prt = c_buf + (size_t)NB * HD;              // 16.78 MB

    cvt_x<<<8192, 256, 0, stream>>>(x, xb);

    const ushort* xb_c = xb;
    void* args[] = {
        (void*)&xb_c, (void*)&hattn, (void*)&A, (void*)&Wx, (void*)&Wh,
        (void*)&Wattn, (void*)&b, (void*)&c_buf, (void*)&a_prt, (void*)&out
    };
    hipLaunchCooperativeKernel((void*)persist, dim3(256), dim3(512),
                               args, 0, stream);
}

// Round 4
// 5561.788 us; speedup vs baseline: 4.7626x; 4.7626x over previous
//
#include <hip/hip_runtime.h>
#include <math.h>

#define NB 128
#define TT 128
#define HD 1024
#define FH 4096
#define KT3 3072
#define KSP 8
#define BKK 384    // K per block = KT3/KSP

typedef __attribute__((ext_vector_type(8))) short short8v;
typedef __attribute__((ext_vector_type(4))) float float4v;

__device__ __forceinline__ ushort f2b(float f) {
    union { float f; unsigned u; } v; v.f = f;
    unsigned r = (v.u + 0x7fffu + ((v.u >> 16) & 1u)) >> 16;
    return (ushort)r;
}

// ---------------------------------------------------------------------------
// x fp32 -> bf16 (layout stays [N][T][D])
__global__ __launch_bounds__(256) void cvt_x(const float* __restrict__ x,
                                             ushort* __restrict__ xb) {
    size_t i = (size_t)blockIdx.x * 256 + threadIdx.x;
    const float4* p = (const float4*)x + i * 2;
    float4 va = p[0], vb = p[1];
    union { ushort u[8]; uint4 v; } o;
    o.u[0] = f2b(va.x); o.u[1] = f2b(va.y); o.u[2] = f2b(va.z); o.u[3] = f2b(va.w);
    o.u[4] = f2b(vb.x); o.u[5] = f2b(vb.y); o.u[6] = f2b(vb.z); o.u[7] = f2b(vb.w);
    ((uint4*)xb)[i] = o.v;
}

// ---------------------------------------------------------------------------
// WT[n][k] = W_seg[k][n] in bf16.  k<1024: Wx, <2048: Wh, else Wattn.
__global__ __launch_bounds__(256) void build_wt(const float* __restrict__ Wx,
                                                const float* __restrict__ Wh,
                                                const float* __restrict__ Wattn,
                                                ushort* __restrict__ WT) {
    __shared__ ushort Ls[64][65];
    int k0 = blockIdx.x * 64, n0 = blockIdx.y * 64;
    const float* W; int kk0;
    if (k0 < 1024)      { W = Wx;    kk0 = k0; }
    else if (k0 < 2048) { W = Wh;    kk0 = k0 - 1024; }
    else                { W = Wattn; kk0 = k0 - 2048; }
    int t = threadIdx.x;
    int cc = t & 63, r4 = t >> 6;
#pragma unroll
    for (int i = 0; i < 16; ++i) {
        int r = i * 4 + r4;
        Ls[r][cc] = f2b(W[(size_t)(kk0 + r) * FH + n0 + cc]);
    }
    __syncthreads();
#pragma unroll
    for (int i = 0; i < 16; ++i) {
        int nn = i * 4 + r4;
        WT[(size_t)(n0 + nn) * KT3 + k0 + cc] = Ls[cc][nn];
    }
}

// ---------------------------------------------------------------------------
// a_part[ks] = Ain[:, ks*384:(ks+1)*384] @ W[...]  (bf16 MFMA, fp32 acc)
// No LDS, no barriers: A and B fragments are 16B contiguous-K global loads.
// grid (64 ntile, KSP); block 512 = 8 waves: mg = w>>2 (64 M-rows), cg = w&3.
__global__ __launch_bounds__(512) void gemm_kernel(
    const ushort* __restrict__ xb_t,    // + row*TT*HD + k      (k < 1024)
    const ushort* __restrict__ hattn,   // [128][2048]          (k >= 1024, h|attn)
    const ushort* __restrict__ WT,      // [4096][3072]
    float* __restrict__ a_part)         // [KSP][128][4096]
{
    const int tid = threadIdx.x;
    const int w = tid >> 6, l = tid & 63;
    const int mg = w >> 2;              // 0..1
    const int cg = w & 3;               // 0..3
    const int lr = l & 15, g = l >> 4;
    const int n0 = blockIdx.x * 64;
    const int ks = blockIdx.y;
    const int col = n0 + cg * 16 + lr;
    const int kb = ks * BKK;

    float4v acc[4];
#pragma unroll
    for (int mf = 0; mf < 4; ++mf) acc[mf] = (float4v){0.f, 0.f, 0.f, 0.f};

    const ushort* Bp = WT + (size_t)col * KT3 + kb + g * 8;
    const int r0 = mg * 64 + lr;
    const ushort* xA[4];
    const ushort* hA[4];
#pragma unroll
    for (int mf = 0; mf < 4; ++mf) {
        xA[mf] = xb_t  + (size_t)(r0 + mf * 16) * (TT * HD) + g * 8;
        hA[mf] = hattn + (size_t)(r0 + mf * 16) * 2048      + g * 8;
    }

#pragma unroll
    for (int s = 0; s < 12; ++s) {
        const int k0 = kb + s * 32;
        short8v b = *(const short8v*)(Bp + s * 32);
        short8v a[4];
        if (k0 < 1024) {
#pragma unroll
            for (int mf = 0; mf < 4; ++mf)
                a[mf] = *(const short8v*)(xA[mf] + k0);
        } else {
#pragma unroll
            for (int mf = 0; mf < 4; ++mf)
                a[mf] = *(const short8v*)(hA[mf] + (k0 - 1024));
        }
#pragma unroll
        for (int mf = 0; mf < 4; ++mf)
            acc[mf] = __builtin_amdgcn_mfma_f32_16x16x32_bf16(a[mf], b, acc[mf], 0, 0, 0);
    }

    float* dst = a_part + (size_t)ks * (NB * FH);
#pragma unroll
    for (int mf = 0; mf < 4; ++mf) {
        const int mrow = mg * 64 + mf * 16 + g * 4;
#pragma unroll
        for (int j = 0; j < 4; ++j)
            dst[(size_t)(mrow + j) * FH + col] = acc[mf][j];
    }
}

// ---------------------------------------------------------------------------
// MODE 0: h0=c0=meanpool(A) then attention.  MODE 1: gates(a)+cell, out, attn.
// 1 block per batch row, 1024 threads (thread = h index).
template <int MODE>
__global__ __launch_bounds__(1024) void fused_kernel(
    const float* __restrict__ a_part,   // [KSP][128][4096]
    const float* __restrict__ bias,     // [4096]
    const float* __restrict__ A,        // [128][1024][16]
    float* __restrict__ c,              // [128][1024]
    ushort* __restrict__ hattn,         // [128][2048] bf16 (h | attn)
    float* __restrict__ out_t)          // + t*HD, row stride TT*HD
{
    __shared__ float red[16][17];
    const int n = blockIdx.x, hh = threadIdx.x;
    const size_t idx = (size_t)n * HD + hh;
    const float4* a4 = (const float4*)(A + idx * 16);
    float4 A0 = a4[0], A1 = a4[1], A2 = a4[2], A3 = a4[3];

    float hv;
    if (MODE == 0) {
        float s = A0.x + A0.y + A0.z + A0.w + A1.x + A1.y + A1.z + A1.w
                + A2.x + A2.y + A2.z + A2.w + A3.x + A3.y + A3.z + A3.w;
        hv = s * 0.0625f;
        c[idx] = hv;
    } else {
        const size_t ab = (size_t)n * FH + hh;
        float ai = bias[hh], af = bias[1024 + hh], ao = bias[2048 + hh], ag = bias[3072 + hh];
#pragma unroll
        for (int ks = 0; ks < KSP; ++ks) {
            const float* ap = a_part + (size_t)ks * (NB * FH) + ab;
            ai += ap[0]; af += ap[1024]; ao += ap[2048]; ag += ap[3072];
        }
        float si = 1.f / (1.f + __expf(-ai));
        float sf = 1.f / (1.f + __expf(-af));
        float so = 1.f / (1.f + __expf(-ao));
        float tg = tanhf(ag);
        float cn = sf * c[idx] + si * tg;
        hv = so * tanhf(cn);
        c[idx] = cn;
        out_t[(size_t)n * (TT * HD) + hh] = hv;
    }
    hattn[(size_t)n * 2048 + hh] = f2b(hv);

    // attention scores: qk[k] = sum_h h*A[n][h][k]
    float p[16];
    p[0]  = hv * A0.x; p[1]  = hv * A0.y; p[2]  = hv * A0.z; p[3]  = hv * A0.w;
    p[4]  = hv * A1.x; p[5]  = hv * A1.y; p[6]  = hv * A1.z; p[7]  = hv * A1.w;
    p[8]  = hv * A2.x; p[9]  = hv * A2.y; p[10] = hv * A2.z; p[11] = hv * A2.w;
    p[12] = hv * A3.x; p[13] = hv * A3.y; p[14] = hv * A3.z; p[15] = hv * A3.w;
#pragma unroll
    for (int k = 0; k < 16; ++k) {
        float v = p[k];
        v += __shfl_xor(v, 32); v += __shfl_xor(v, 16); v += __shfl_xor(v, 8);
        v += __shfl_xor(v, 4);  v += __shfl_xor(v, 2);  v += __shfl_xor(v, 1);
        p[k] = v;
    }
    const int wv = hh >> 6;
    if ((hh & 63) == 0) {
#pragma unroll
        for (int k = 0; k < 16; ++k) red[wv][k] = p[k];
    }
    __syncthreads();
    float qk[16], mx = -1e30f;
#pragma unroll
    for (int k = 0; k < 16; ++k) {
        float s = 0.f;
#pragma unroll
        for (int w2 = 0; w2 < 16; ++w2) s += red[w2][k];
        qk[k] = s * 0.03125f;             // 1/sqrt(1024)
        mx = fmaxf(mx, qk[k]);
    }
    float sum = 0.f;
#pragma unroll
    for (int k = 0; k < 16; ++k) { qk[k] = __expf(qk[k] - mx); sum += qk[k]; }
    float inv = 1.f / sum;
    float av = qk[0]*A0.x + qk[1]*A0.y + qk[2]*A0.z + qk[3]*A0.w
             + qk[4]*A1.x + qk[5]*A1.y + qk[6]*A1.z + qk[7]*A1.w
             + qk[8]*A2.x + qk[9]*A2.y + qk[10]*A2.z + qk[11]*A2.w
             + qk[12]*A3.x + qk[13]*A3.y + qk[14]*A3.z + qk[15]*A3.w;
    av *= inv;
    hattn[(size_t)n * 2048 + 1024 + hh] = f2b(av);
}

// ---------------------------------------------------------------------------
extern "C" void kernel_launch(void* const* d_in, const int* in_sizes, int n_in,
                              void* d_out, int out_size, void* d_ws, size_t ws_size,
                              hipStream_t stream) {
    const float* x     = (const float*)d_in[0];
    const float* A     = (const float*)d_in[1];
    const float* Wx    = (const float*)d_in[2];
    const float* Wh    = (const float*)d_in[3];
    const float* Wattn = (const float*)d_in[4];
    const float* b     = (const float*)d_in[5];
    float* out = (float*)d_out;

    ushort* WT    = (ushort*)d_ws;                        // 4096*3072 bf16 = 25.2 MB
    ushort* xb    = WT + (size_t)FH * KT3;                // 33.55 MB
    ushort* hattn = xb + (size_t)NB * TT * HD;            // 0.5 MB
    float*  c_buf = (float*)(hattn + (size_t)NB * 2048);  // 0.5 MB
    float*  a_prt = c_buf + (size_t)NB * HD;              // KSP*128*4096 fp32 = 16.8 MB

    cvt_x<<<8192, 256, 0, stream>>>(x, xb);
    build_wt<<<dim3(48, 64), 256, 0, stream>>>(Wx, Wh, Wattn, WT);
    fused_kernel<0><<<NB, 1024, 0, stream>>>(a_prt, b, A, c_buf, hattn, out);

    for (int t = 0; t < TT; ++t) {
        gemm_kernel<<<dim3(64, KSP), 512, 0, stream>>>(
            xb + (size_t)t * HD, hattn, WT, a_prt);
        fused_kernel<1><<<NB, 1024, 0, stream>>>(
            a_prt, b, A, c_buf, hattn, out + (size_t)t * HD);
    }
}

// Round 5
// 3504.149 us; speedup vs baseline: 7.5592x; 1.5872x over previous
//
#include <hip/hip_runtime.h>
#include <math.h>

#define NB 128
#define TT 128
#define HD 1024
#define FH 4096
#define KT3 3072

typedef __attribute__((ext_vector_type(8))) short short8v;
typedef __attribute__((ext_vector_type(4))) float float4v;

__device__ __forceinline__ ushort f2b(float f) {
    union { float f; unsigned u; } v; v.f = f;
    unsigned r = (v.u + 0x7fffu + ((v.u >> 16) & 1u)) >> 16;
    return (ushort)r;
}
__device__ __forceinline__ float b2f(ushort u) {
    union { unsigned u; float f; } v; v.u = ((unsigned)u) << 16;
    return v.f;
}
__device__ __forceinline__ void gll16(const void* g, void* l) {
    __builtin_amdgcn_global_load_lds(
        (const __attribute__((address_space(1))) void*)g,
        (__attribute__((address_space(3))) void*)l,
        16, 0, 0);
}
// XOR chunk swizzle within a 16-chunk (256B) row; involution in low 3 bits.
__device__ __forceinline__ int swz(int c, int r) {
    return (c & 8) | ((c & 7) ^ (r & 7));
}

// ---------------------------------------------------------------------------
// x fp32 -> bf16 (layout stays [N][T][D])
__global__ __launch_bounds__(256) void cvt_x(const float* __restrict__ x,
                                             ushort* __restrict__ xb) {
    size_t i = (size_t)blockIdx.x * 256 + threadIdx.x;
    const float4* p = (const float4*)x + i * 2;
    float4 va = p[0], vb = p[1];
    union { ushort u[8]; uint4 v; } o;
    o.u[0] = f2b(va.x); o.u[1] = f2b(va.y); o.u[2] = f2b(va.z); o.u[3] = f2b(va.w);
    o.u[4] = f2b(vb.x); o.u[5] = f2b(vb.y); o.u[6] = f2b(vb.z); o.u[7] = f2b(vb.w);
    ((uint4*)xb)[i] = o.v;
}

// ---------------------------------------------------------------------------
// WT[n][k] = W_seg[k][n] in bf16.  k<1024: Wx, <2048: Wh, else Wattn.
__global__ __launch_bounds__(256) void build_wt(const float* __restrict__ Wx,
                                                const float* __restrict__ Wh,
                                                const float* __restrict__ Wattn,
                                                ushort* __restrict__ WT) {
    __shared__ ushort Ls[64][65];
    int k0 = blockIdx.x * 64, n0 = blockIdx.y * 64;
    const float* W; int kk0;
    if (k0 < 1024)      { W = Wx;    kk0 = k0; }
    else if (k0 < 2048) { W = Wh;    kk0 = k0 - 1024; }
    else                { W = Wattn; kk0 = k0 - 2048; }
    int t = threadIdx.x;
    int cc = t & 63, r4 = t >> 6;
#pragma unroll
    for (int i = 0; i < 16; ++i) {
        int r = i * 4 + r4;
        Ls[r][cc] = f2b(W[(size_t)(kk0 + r) * FH + n0 + cc]);
    }
    __syncthreads();
#pragma unroll
    for (int i = 0; i < 16; ++i) {
        int nn = i * 4 + r4;
        WT[(size_t)(n0 + nn) * KT3 + k0 + cc] = Ls[cc][nn];
    }
}

// ---------------------------------------------------------------------------
// XA[t][n][:] = x[n,t,:] @ Wx   (one big GEMM, 16384 x 1024 x 4096)
// block: 128 M-rows (= one n, all t? no: rows m = mt*128+rl -> n=mt, t=rl),
// 128 N-cols, K=1024 in 8 substeps of 128, double-buffered LDS.
template <int F32OUT>
__global__ __launch_bounds__(256, 1) void xa_gemm(
    const ushort* __restrict__ xb,      // [16384][1024]
    const ushort* __restrict__ WT,      // [4096][3072]
    float* __restrict__ xaf,
    ushort* __restrict__ xab)
{
    __shared__ ushort As[2][128 * 128];
    __shared__ ushort Bs[2][128 * 128];
    const int tid = threadIdx.x;
    const int w = tid >> 6, l = tid & 63;
    const int wm = w >> 1, wn = w & 1;
    const int lr = l & 15, g = l >> 4;
    const int n0 = blockIdx.x * 128;
    const int mt = blockIdx.y;
    const ushort* Abase = xb + (size_t)mt * 128 * 1024;
    const ushort* Bbase = WT + (size_t)n0 * KT3;

    float4v acc[4][4];
#pragma unroll
    for (int i = 0; i < 4; ++i)
#pragma unroll
        for (int j = 0; j < 4; ++j) acc[i][j] = (float4v){0.f, 0.f, 0.f, 0.f};

    int buf = 0;
    // stage substep 0
#pragma unroll
    for (int i = 0; i < 8; ++i) {
        int s = i * 256 + w * 64 + l;
        int r = s >> 4, c = swz(s & 15, r);
        gll16(Abase + (size_t)r * 1024 + c * 8, &As[0][(i * 256 + w * 64) * 8]);
    }
#pragma unroll
    for (int i = 0; i < 8; ++i) {
        int s = i * 256 + w * 64 + l;
        int r = s >> 4, c = swz(s & 15, r);
        gll16(Bbase + (size_t)r * KT3 + c * 8, &Bs[0][(i * 256 + w * 64) * 8]);
    }
    __syncthreads();

#pragma unroll 1
    for (int ks = 0; ks < 8; ++ks) {
        if (ks < 7) {
            const int kf = (ks + 1) * 128;
#pragma unroll
            for (int i = 0; i < 8; ++i) {
                int s = i * 256 + w * 64 + l;
                int r = s >> 4, c = swz(s & 15, r);
                gll16(Abase + (size_t)r * 1024 + kf + c * 8,
                      &As[buf ^ 1][(i * 256 + w * 64) * 8]);
            }
#pragma unroll
            for (int i = 0; i < 8; ++i) {
                int s = i * 256 + w * 64 + l;
                int r = s >> 4, c = swz(s & 15, r);
                gll16(Bbase + (size_t)r * KT3 + kf + c * 8,
                      &Bs[buf ^ 1][(i * 256 + w * 64) * 8]);
            }
        }
        const ushort* Ab = As[buf];
        const ushort* Bb = Bs[buf];
#pragma unroll
        for (int s4 = 0; s4 < 4; ++s4) {
            short8v af[4], bf[4];
#pragma unroll
            for (int mf = 0; mf < 4; ++mf) {
                int r = wm * 64 + mf * 16 + lr;
                af[mf] = *(const short8v*)&Ab[r * 128 + swz(s4 * 4 + g, r) * 8];
            }
#pragma unroll
            for (int nf = 0; nf < 4; ++nf) {
                int r = wn * 64 + nf * 16 + lr;
                bf[nf] = *(const short8v*)&Bb[r * 128 + swz(s4 * 4 + g, r) * 8];
            }
#pragma unroll
            for (int mf = 0; mf < 4; ++mf)
#pragma unroll
                for (int nf = 0; nf < 4; ++nf)
                    acc[mf][nf] = __builtin_amdgcn_mfma_f32_16x16x32_bf16(
                        af[mf], bf[nf], acc[mf][nf], 0, 0, 0);
        }
        __syncthreads();
        buf ^= 1;
    }

#pragma unroll
    for (int mf = 0; mf < 4; ++mf)
#pragma unroll
        for (int nf = 0; nf < 4; ++nf) {
            const int col = n0 + wn * 64 + nf * 16 + lr;
#pragma unroll
            for (int j = 0; j < 4; ++j) {
                const int rl = wm * 64 + mf * 16 + g * 4 + j;   // = t
                const size_t idx = ((size_t)rl * NB + mt) * FH + col;
                if (F32OUT) xaf[idx] = acc[mf][nf][j];
                else        xab[idx] = f2b(acc[mf][nf][j]);
            }
        }
}

// ---------------------------------------------------------------------------
// Per-step GEMM: a_part[by] = Ain[:, kq*128:(kq+1)*128] @ W[...]
// FULLK: kq = by in [0,24) over [x_t|h|attn]; else kq = by+8 in [8,24) over
// [h|attn] (XA precomputed). BM=128, BN=256, BK=128; 8 waves of 64x64.
template <bool FULLK>
__global__ __launch_bounds__(512, 2) void step_gemm(
    const ushort* __restrict__ xb_t,    // + r*TT*HD (FULLK only)
    const ushort* __restrict__ hattn,   // [128][2048]
    const ushort* __restrict__ WT,      // [4096][3072]
    float* __restrict__ a_part)         // [gridDim.y][128][4096]
{
    __shared__ ushort As[128 * 128];    // 32 KB
    __shared__ ushort Bs[256 * 128];    // 64 KB
    const int tid = threadIdx.x;
    const int w = tid >> 6, l = tid & 63;
    const int wm = w >> 2, wn = w & 3;
    const int lr = l & 15, g = l >> 4;
    const int n0 = blockIdx.x * 256;
    const int kq = blockIdx.y + (FULLK ? 0 : 8);

    const ushort* asrc; size_t astr; int koff;
    if (FULLK && kq < 8) { asrc = xb_t;  astr = (size_t)TT * HD; koff = kq * 128; }
    else                 { asrc = hattn; astr = 2048;            koff = kq * 128 - 1024; }

#pragma unroll
    for (int i = 0; i < 4; ++i) {       // A: 2048 chunks
        int s = i * 512 + w * 64 + l;
        int r = s >> 4, c = swz(s & 15, r);
        gll16(asrc + (size_t)r * astr + koff + c * 8, &As[(i * 512 + w * 64) * 8]);
    }
    const ushort* Bbase = WT + (size_t)n0 * KT3 + kq * 128;
#pragma unroll
    for (int i = 0; i < 8; ++i) {       // B: 4096 chunks
        int s = i * 512 + w * 64 + l;
        int r = s >> 4, c = swz(s & 15, r);
        gll16(Bbase + (size_t)r * KT3 + c * 8, &Bs[(i * 512 + w * 64) * 8]);
    }
    __syncthreads();

    float4v acc[4][4];
#pragma unroll
    for (int i = 0; i < 4; ++i)
#pragma unroll
        for (int j = 0; j < 4; ++j) acc[i][j] = (float4v){0.f, 0.f, 0.f, 0.f};

#pragma unroll
    for (int s4 = 0; s4 < 4; ++s4) {
        short8v af[4], bf[4];
#pragma unroll
        for (int mf = 0; mf < 4; ++mf) {
            int r = wm * 64 + mf * 16 + lr;
            af[mf] = *(const short8v*)&As[r * 128 + swz(s4 * 4 + g, r) * 8];
        }
#pragma unroll
        for (int nf = 0; nf < 4; ++nf) {
            int r = wn * 64 + nf * 16 + lr;
            bf[nf] = *(const short8v*)&Bs[r * 128 + swz(s4 * 4 + g, r) * 8];
        }
#pragma unroll
        for (int mf = 0; mf < 4; ++mf)
#pragma unroll
            for (int nf = 0; nf < 4; ++nf)
                acc[mf][nf] = __builtin_amdgcn_mfma_f32_16x16x32_bf16(
                    af[mf], bf[nf], acc[mf][nf], 0, 0, 0);
    }

    float* dst = a_part + (size_t)blockIdx.y * (NB * FH);
#pragma unroll
    for (int mf = 0; mf < 4; ++mf)
#pragma unroll
        for (int nf = 0; nf < 4; ++nf) {
            const int col = n0 + wn * 64 + nf * 16 + lr;
#pragma unroll
            for (int j = 0; j < 4; ++j) {
                const int row = wm * 64 + mf * 16 + g * 4 + j;
                dst[(size_t)row * FH + col] = acc[mf][nf][j];
            }
        }
}

// ---------------------------------------------------------------------------
// MODE 0: h0=c0=meanpool(A) then attention.  MODE 1: gates+cell, out, attn.
// XAF: 0 none, 1 bf16 XA, 2 fp32 XA. NSLICE partial slices in a_part.
template <int MODE, int NSLICE, int XAF>
__global__ __launch_bounds__(1024) void fused_kernel(
    const float* __restrict__ a_part,
    const float* __restrict__ xaf,      // + t*NB*FH
    const ushort* __restrict__ xab,     // + t*NB*FH
    const float* __restrict__ bias,
    const float* __restrict__ A,
    float* __restrict__ c,
    ushort* __restrict__ hattn,
    float* __restrict__ out_t)          // + t*HD, row stride TT*HD
{
    __shared__ float red[16][17];
    const int n = blockIdx.x, hh = threadIdx.x;
    const size_t idx = (size_t)n * HD + hh;
    const float4* a4 = (const float4*)(A + idx * 16);
    float4 A0 = a4[0], A1 = a4[1], A2 = a4[2], A3 = a4[3];

    float hv;
    if (MODE == 0) {
        float s = A0.x + A0.y + A0.z + A0.w + A1.x + A1.y + A1.z + A1.w
                + A2.x + A2.y + A2.z + A2.w + A3.x + A3.y + A3.z + A3.w;
        hv = s * 0.0625f;
        c[idx] = hv;
    } else {
        const size_t ab = (size_t)n * FH + hh;
        float ai = bias[hh], af = bias[1024 + hh], ao = bias[2048 + hh], ag = bias[3072 + hh];
        if (XAF == 2) {
            const float* xp = xaf + ab;
            ai += xp[0]; af += xp[1024]; ao += xp[2048]; ag += xp[3072];
        } else if (XAF == 1) {
            const ushort* xp = xab + ab;
            ai += b2f(xp[0]); af += b2f(xp[1024]); ao += b2f(xp[2048]); ag += b2f(xp[3072]);
        }
#pragma unroll
        for (int ks = 0; ks < NSLICE; ++ks) {
            const float* ap = a_part + (size_t)ks * (NB * FH) + ab;
            ai += ap[0]; af += ap[1024]; ao += ap[2048]; ag += ap[3072];
        }
        float si = 1.f / (1.f + __expf(-ai));
        float sf = 1.f / (1.f + __expf(-af));
        float so = 1.f / (1.f + __expf(-ao));
        float tg = tanhf(ag);
        float cn = sf * c[idx] + si * tg;
        hv = so * tanhf(cn);
        c[idx] = cn;
        out_t[(size_t)n * (TT * HD) + hh] = hv;
    }
    hattn[(size_t)n * 2048 + hh] = f2b(hv);

    float p[16];
    p[0]  = hv * A0.x; p[1]  = hv * A0.y; p[2]  = hv * A0.z; p[3]  = hv * A0.w;
    p[4]  = hv * A1.x; p[5]  = hv * A1.y; p[6]  = hv * A1.z; p[7]  = hv * A1.w;
    p[8]  = hv * A2.x; p[9]  = hv * A2.y; p[10] = hv * A2.z; p[11] = hv * A2.w;
    p[12] = hv * A3.x; p[13] = hv * A3.y; p[14] = hv * A3.z; p[15] = hv * A3.w;
#pragma unroll
    for (int k = 0; k < 16; ++k) {
        float v = p[k];
        v += __shfl_xor(v, 32); v += __shfl_xor(v, 16); v += __shfl_xor(v, 8);
        v += __shfl_xor(v, 4);  v += __shfl_xor(v, 2);  v += __shfl_xor(v, 1);
        p[k] = v;
    }
    const int wv = hh >> 6;
    if ((hh & 63) == 0) {
#pragma unroll
        for (int k = 0; k < 16; ++k) red[wv][k] = p[k];
    }
    __syncthreads();
    float qk[16], mx = -1e30f;
#pragma unroll
    for (int k = 0; k < 16; ++k) {
        float s = 0.f;
#pragma unroll
        for (int w2 = 0; w2 < 16; ++w2) s += red[w2][k];
        qk[k] = s * 0.03125f;             // 1/sqrt(1024)
        mx = fmaxf(mx, qk[k]);
    }
    float sum = 0.f;
#pragma unroll
    for (int k = 0; k < 16; ++k) { qk[k] = __expf(qk[k] - mx); sum += qk[k]; }
    float inv = 1.f / sum;
    float av = qk[0]*A0.x + qk[1]*A0.y + qk[2]*A0.z + qk[3]*A0.w
             + qk[4]*A1.x + qk[5]*A1.y + qk[6]*A1.z + qk[7]*A1.w
             + qk[8]*A2.x + qk[9]*A2.y + qk[10]*A2.z + qk[11]*A2.w
             + qk[12]*A3.x + qk[13]*A3.y + qk[14]*A3.z + qk[15]*A3.w;
    av *= inv;
    hattn[(size_t)n * 2048 + 1024 + hh] = f2b(av);
}

// ---------------------------------------------------------------------------
extern "C" void kernel_launch(void* const* d_in, const int* in_sizes, int n_in,
                              void* d_out, int out_size, void* d_ws, size_t ws_size,
                              hipStream_t stream) {
    const float* x     = (const float*)d_in[0];
    const float* A     = (const float*)d_in[1];
    const float* Wx    = (const float*)d_in[2];
    const float* Wh    = (const float*)d_in[3];
    const float* Wattn = (const float*)d_in[4];
    const float* b     = (const float*)d_in[5];
    float* out = (float*)d_out;

    ushort* WT    = (ushort*)d_ws;                        // 25.17 MB
    ushort* xb    = WT + (size_t)FH * KT3;                // 33.55 MB
    ushort* hattn = xb + (size_t)NB * TT * HD;            // 0.5 MB
    float*  c_buf = (float*)(hattn + (size_t)NB * 2048);  // 0.5 MB
    float*  a_prt = c_buf + (size_t)NB * HD;              // 16 or 24 slices

    const size_t base   = 25165824ull + 33554432ull + 524288ull + 524288ull;
    const size_t ap16   = 16ull * NB * FH * 4;            // 33.55 MB
    const size_t ap24   = 24ull * NB * FH * 4;            // 50.33 MB
    const size_t xaf32  = (size_t)TT * NB * FH * 4;       // 268.4 MB
    const size_t xab16  = xaf32 / 2;                      // 134.2 MB

    cvt_x<<<8192, 256, 0, stream>>>(x, xb);
    build_wt<<<dim3(48, 64), 256, 0, stream>>>(Wx, Wh, Wattn, WT);
    fused_kernel<0, 16, 0><<<NB, 1024, 0, stream>>>(
        a_prt, nullptr, nullptr, b, A, c_buf, hattn, out);

    if (ws_size >= base + ap16 + xaf32) {
        float* xa = (float*)((char*)d_ws + base + ap16);
        xa_gemm<1><<<dim3(32, 128), 256, 0, stream>>>(xb, WT, xa, nullptr);
        for (int t = 0; t < TT; ++t) {
            step_gemm<false><<<dim3(16, 16), 512, 0, stream>>>(nullptr, hattn, WT, a_prt);
            fused_kernel<1, 16, 2><<<NB, 1024, 0, stream>>>(
                a_prt, xa + (size_t)t * NB * FH, nullptr, b, A, c_buf, hattn,
                out + (size_t)t * HD);
        }
    } else if (ws_size >= base + ap16 + xab16) {
        ushort* xa = (ushort*)((char*)d_ws + base + ap16);
        xa_gemm<0><<<dim3(32, 128), 256, 0, stream>>>(xb, WT, nullptr, xa);
        for (int t = 0; t < TT; ++t) {
            step_gemm<false><<<dim3(16, 16), 512, 0, stream>>>(nullptr, hattn, WT, a_prt);
            fused_kernel<1, 16, 1><<<NB, 1024, 0, stream>>>(
                a_prt, nullptr, xa + (size_t)t * NB * FH, b, A, c_buf, hattn,
                out + (size_t)t * HD);
        }
    } else {
        for (int t = 0; t < TT; ++t) {
            step_gemm<true><<<dim3(16, 24), 512, 0, stream>>>(
                xb + (size_t)t * HD, hattn, WT, a_prt);
            fused_kernel<1, 24, 0><<<NB, 1024, 0, stream>>>(
                a_prt, nullptr, nullptr, b, A, c_buf, hattn,
                out + (size_t)t * HD);
        }
    }
}

// Round 6
// 3483.361 us; speedup vs baseline: 7.6043x; 1.0060x over previous
//
#include <hip/hip_runtime.h>
#include <math.h>

#define NB 128
#define TT 128
#define HD 1024
#define FH 4096
#define KT3 3072

typedef __attribute__((ext_vector_type(8))) short short8v;
typedef __attribute__((ext_vector_type(4))) float float4v;

__device__ __forceinline__ ushort f2b(float f) {
    union { float f; unsigned u; } v; v.f = f;
    unsigned r = (v.u + 0x7fffu + ((v.u >> 16) & 1u)) >> 16;
    return (ushort)r;
}
__device__ __forceinline__ float b2f(ushort u) {
    union { unsigned u; float f; } v; v.u = ((unsigned)u) << 16;
    return v.f;
}
__device__ __forceinline__ void gll16(const void* g, void* l) {
    __builtin_amdgcn_global_load_lds(
        (const __attribute__((address_space(1))) void*)g,
        (__attribute__((address_space(3))) void*)l,
        16, 0, 0);
}
// XOR chunk swizzle within a 16-chunk (256B) row; involution in low 3 bits.
__device__ __forceinline__ int swz(int c, int r) {
    return (c & 8) | ((c & 7) ^ (r & 7));
}

// ---------------------------------------------------------------------------
// x fp32 -> bf16 (layout stays [N][T][D])
__global__ __launch_bounds__(256) void cvt_x(const float* __restrict__ x,
                                             ushort* __restrict__ xb) {
    size_t i = (size_t)blockIdx.x * 256 + threadIdx.x;
    const float4* p = (const float4*)x + i * 2;
    float4 va = p[0], vb = p[1];
    union { ushort u[8]; uint4 v; } o;
    o.u[0] = f2b(va.x); o.u[1] = f2b(va.y); o.u[2] = f2b(va.z); o.u[3] = f2b(va.w);
    o.u[4] = f2b(vb.x); o.u[5] = f2b(vb.y); o.u[6] = f2b(vb.z); o.u[7] = f2b(vb.w);
    ((uint4*)xb)[i] = o.v;
}

// ---------------------------------------------------------------------------
// WT[n][k] = W_seg[k][n] in bf16.  k<1024: Wx, <2048: Wh, else Wattn.
__global__ __launch_bounds__(256) void build_wt(const float* __restrict__ Wx,
                                                const float* __restrict__ Wh,
                                                const float* __restrict__ Wattn,
                                                ushort* __restrict__ WT) {
    __shared__ ushort Ls[64][65];
    int k0 = blockIdx.x * 64, n0 = blockIdx.y * 64;
    const float* W; int kk0;
    if (k0 < 1024)      { W = Wx;    kk0 = k0; }
    else if (k0 < 2048) { W = Wh;    kk0 = k0 - 1024; }
    else                { W = Wattn; kk0 = k0 - 2048; }
    int t = threadIdx.x;
    int cc = t & 63, r4 = t >> 6;
#pragma unroll
    for (int i = 0; i < 16; ++i) {
        int r = i * 4 + r4;
        Ls[r][cc] = f2b(W[(size_t)(kk0 + r) * FH + n0 + cc]);
    }
    __syncthreads();
#pragma unroll
    for (int i = 0; i < 16; ++i) {
        int nn = i * 4 + r4;
        WT[(size_t)(n0 + nn) * KT3 + k0 + cc] = Ls[cc][nn];
    }
}

// ---------------------------------------------------------------------------
// XA[t][n][:] = x[n,t,:] @ Wx   (one big GEMM, 16384 x 1024 x 4096)
template <int F32OUT>
__global__ __launch_bounds__(256, 1) void xa_gemm(
    const ushort* __restrict__ xb,      // [16384][1024]
    const ushort* __restrict__ WT,      // [4096][3072]
    float* __restrict__ xaf,
    ushort* __restrict__ xab)
{
    __shared__ ushort As[2][128 * 128];
    __shared__ ushort Bs[2][128 * 128];
    const int tid = threadIdx.x;
    const int w = tid >> 6, l = tid & 63;
    const int wm = w >> 1, wn = w & 1;
    const int lr = l & 15, g = l >> 4;
    const int n0 = blockIdx.x * 128;
    const int mt = blockIdx.y;
    const ushort* Abase = xb + (size_t)mt * 128 * 1024;
    const ushort* Bbase = WT + (size_t)n0 * KT3;

    float4v acc[4][4];
#pragma unroll
    for (int i = 0; i < 4; ++i)
#pragma unroll
        for (int j = 0; j < 4; ++j) acc[i][j] = (float4v){0.f, 0.f, 0.f, 0.f};

    int buf = 0;
#pragma unroll
    for (int i = 0; i < 8; ++i) {
        int s = i * 256 + w * 64 + l;
        int r = s >> 4, c = swz(s & 15, r);
        gll16(Abase + (size_t)r * 1024 + c * 8, &As[0][(i * 256 + w * 64) * 8]);
    }
#pragma unroll
    for (int i = 0; i < 8; ++i) {
        int s = i * 256 + w * 64 + l;
        int r = s >> 4, c = swz(s & 15, r);
        gll16(Bbase + (size_t)r * KT3 + c * 8, &Bs[0][(i * 256 + w * 64) * 8]);
    }
    __syncthreads();

#pragma unroll 1
    for (int ks = 0; ks < 8; ++ks) {
        if (ks < 7) {
            const int kf = (ks + 1) * 128;
#pragma unroll
            for (int i = 0; i < 8; ++i) {
                int s = i * 256 + w * 64 + l;
                int r = s >> 4, c = swz(s & 15, r);
                gll16(Abase + (size_t)r * 1024 + kf + c * 8,
                      &As[buf ^ 1][(i * 256 + w * 64) * 8]);
            }
#pragma unroll
            for (int i = 0; i < 8; ++i) {
                int s = i * 256 + w * 64 + l;
                int r = s >> 4, c = swz(s & 15, r);
                gll16(Bbase + (size_t)r * KT3 + kf + c * 8,
                      &Bs[buf ^ 1][(i * 256 + w * 64) * 8]);
            }
        }
        const ushort* Ab = As[buf];
        const ushort* Bb = Bs[buf];
#pragma unroll
        for (int s4 = 0; s4 < 4; ++s4) {
            short8v af[4], bf[4];
#pragma unroll
            for (int mf = 0; mf < 4; ++mf) {
                int r = wm * 64 + mf * 16 + lr;
                af[mf] = *(const short8v*)&Ab[r * 128 + swz(s4 * 4 + g, r) * 8];
            }
#pragma unroll
            for (int nf = 0; nf < 4; ++nf) {
                int r = wn * 64 + nf * 16 + lr;
                bf[nf] = *(const short8v*)&Bb[r * 128 + swz(s4 * 4 + g, r) * 8];
            }
#pragma unroll
            for (int mf = 0; mf < 4; ++mf)
#pragma unroll
                for (int nf = 0; nf < 4; ++nf)
                    acc[mf][nf] = __builtin_amdgcn_mfma_f32_16x16x32_bf16(
                        af[mf], bf[nf], acc[mf][nf], 0, 0, 0);
        }
        __syncthreads();
        buf ^= 1;
    }

#pragma unroll
    for (int mf = 0; mf < 4; ++mf)
#pragma unroll
        for (int nf = 0; nf < 4; ++nf) {
            const int col = n0 + wn * 64 + nf * 16 + lr;
#pragma unroll
            for (int j = 0; j < 4; ++j) {
                const int rl = wm * 64 + mf * 16 + g * 4 + j;   // = t
                const size_t idx = ((size_t)rl * NB + mt) * FH + col;
                if (F32OUT) xaf[idx] = acc[mf][nf][j];
                else        xab[idx] = f2b(acc[mf][nf][j]);
            }
        }
}

// ---------------------------------------------------------------------------
// Per-step GEMM v2: K-looped, double-buffered, BM=128 BN=128 BK=64.
// FULLK: kq in [0,6) over [x_t|h|attn] (K=512 each); else kq in [0,4) over
// [h|attn] (K=512 each, XA precomputed). Grid (32, KSP); 256 thr = 4 waves
// of 64x64 tiles (0.5 ds_read/MFMA).
template <bool FULLK>
__global__ __launch_bounds__(256, 2) void step_gemm(
    const ushort* __restrict__ xb_t,    // + r*TT*HD (FULLK, kq<2)
    const ushort* __restrict__ hattn,   // [128][2048]
    const ushort* __restrict__ WT,      // [4096][3072]
    float* __restrict__ a_part)         // [KSP][128][4096]
{
    __shared__ ushort As[2][128 * 64];  // 16 KB each
    __shared__ ushort Bs[2][128 * 64];
    const int tid = threadIdx.x;
    const int w = tid >> 6, l = tid & 63;
    const int wm = w >> 1, wn = w & 1;
    const int lr = l & 15, g = l >> 4;
    const int n0 = blockIdx.x * 128;
    const int kq = blockIdx.y;
    const int kbase = FULLK ? kq * 512 : (1024 + kq * 512);

    // whole block's K-range lies in one segment (512-aligned)
    const ushort* asrc; size_t astr; int kloc;
    if (FULLK && kbase < 1024) { asrc = xb_t;  astr = (size_t)TT * HD; kloc = kbase; }
    else                       { asrc = hattn; astr = 2048;            kloc = kbase - 1024; }
    const ushort* Bbase = WT + (size_t)n0 * KT3 + kbase;

    float4v acc[4][4];
#pragma unroll
    for (int i = 0; i < 4; ++i)
#pragma unroll
        for (int j = 0; j < 4; ++j) acc[i][j] = (float4v){0.f, 0.f, 0.f, 0.f};

    // stage chunk kc into buffer b: rows 0..127, 8 chunks of 8 elems (16B)
#define STAGE(b, kc)                                                          \
    do {                                                                      \
        const int koff = (kc) * 64;                                          \
        _Pragma("unroll")                                                     \
        for (int i = 0; i < 4; ++i) {                                        \
            int s = i * 256 + w * 64 + l;                                    \
            int r = s >> 3, c = (s & 7) ^ (r & 7);                           \
            gll16(asrc + (size_t)r * astr + kloc + koff + c * 8,             \
                  &As[b][(i * 256 + w * 64) * 8]);                           \
        }                                                                     \
        _Pragma("unroll")                                                     \
        for (int i = 0; i < 4; ++i) {                                        \
            int s = i * 256 + w * 64 + l;                                    \
            int r = s >> 3, c = (s & 7) ^ (r & 7);                           \
            gll16(Bbase + (size_t)r * KT3 + koff + c * 8,                    \
                  &Bs[b][(i * 256 + w * 64) * 8]);                           \
        }                                                                     \
    } while (0)

    STAGE(0, 0);
    __syncthreads();

    int buf = 0;
#pragma unroll 1
    for (int kc = 0; kc < 8; ++kc) {
        if (kc < 7) STAGE(buf ^ 1, kc + 1);
        const ushort* Ab = As[buf];
        const ushort* Bb = Bs[buf];
#pragma unroll
        for (int j = 0; j < 2; ++j) {
            short8v af[4], bf[4];
#pragma unroll
            for (int mf = 0; mf < 4; ++mf) {
                int r = wm * 64 + mf * 16 + lr;
                af[mf] = *(const short8v*)&Ab[r * 64 + ((j * 4 + g) ^ (r & 7)) * 8];
            }
#pragma unroll
            for (int nf = 0; nf < 4; ++nf) {
                int rn = wn * 64 + nf * 16 + lr;
                bf[nf] = *(const short8v*)&Bb[rn * 64 + ((j * 4 + g) ^ (rn & 7)) * 8];
            }
#pragma unroll
            for (int mf = 0; mf < 4; ++mf)
#pragma unroll
                for (int nf = 0; nf < 4; ++nf)
                    acc[mf][nf] = __builtin_amdgcn_mfma_f32_16x16x32_bf16(
                        af[mf], bf[nf], acc[mf][nf], 0, 0, 0);
        }
        __syncthreads();
        buf ^= 1;
    }
#undef STAGE

    float* dst = a_part + (size_t)kq * (NB * FH);
#pragma unroll
    for (int mf = 0; mf < 4; ++mf)
#pragma unroll
        for (int nf = 0; nf < 4; ++nf) {
            const int col = n0 + wn * 64 + nf * 16 + lr;
#pragma unroll
            for (int j = 0; j < 4; ++j) {
                const int row = wm * 64 + mf * 16 + g * 4 + j;
                dst[(size_t)row * FH + col] = acc[mf][nf][j];
            }
        }
}

// ---------------------------------------------------------------------------
// MODE 0: h0=c0=meanpool(A) then attention.  MODE 1: gates+cell, out, attn.
// XAF: 0 none, 1 bf16 XA, 2 fp32 XA. NSLICE partial slices in a_part.
template <int MODE, int NSLICE, int XAF>
__global__ __launch_bounds__(1024) void fused_kernel(
    const float* __restrict__ a_part,
    const float* __restrict__ xaf,      // + t*NB*FH
    const ushort* __restrict__ xab,     // + t*NB*FH
    const float* __restrict__ bias,
    const float* __restrict__ A,
    float* __restrict__ c,
    ushort* __restrict__ hattn,
    float* __restrict__ out_t)          // + t*HD, row stride TT*HD
{
    __shared__ float red[16][17];
    const int n = blockIdx.x, hh = threadIdx.x;
    const size_t idx = (size_t)n * HD + hh;
    const float4* a4 = (const float4*)(A + idx * 16);
    float4 A0 = a4[0], A1 = a4[1], A2 = a4[2], A3 = a4[3];

    float hv;
    if (MODE == 0) {
        float s = A0.x + A0.y + A0.z + A0.w + A1.x + A1.y + A1.z + A1.w
                + A2.x + A2.y + A2.z + A2.w + A3.x + A3.y + A3.z + A3.w;
        hv = s * 0.0625f;
        c[idx] = hv;
    } else {
        const size_t ab = (size_t)n * FH + hh;
        float ai = bias[hh], af = bias[1024 + hh], ao = bias[2048 + hh], ag = bias[3072 + hh];
        if (XAF == 2) {
            const float* xp = xaf + ab;
            ai += xp[0]; af += xp[1024]; ao += xp[2048]; ag += xp[3072];
        } else if (XAF == 1) {
            const ushort* xp = xab + ab;
            ai += b2f(xp[0]); af += b2f(xp[1024]); ao += b2f(xp[2048]); ag += b2f(xp[3072]);
        }
#pragma unroll
        for (int ks = 0; ks < NSLICE; ++ks) {
            const float* ap = a_part + (size_t)ks * (NB * FH) + ab;
            ai += ap[0]; af += ap[1024]; ao += ap[2048]; ag += ap[3072];
        }
        float si = 1.f / (1.f + __expf(-ai));
        float sf = 1.f / (1.f + __expf(-af));
        float so = 1.f / (1.f + __expf(-ao));
        float tg = tanhf(ag);
        float cn = sf * c[idx] + si * tg;
        hv = so * tanhf(cn);
        c[idx] = cn;
        out_t[(size_t)n * (TT * HD) + hh] = hv;
    }
    hattn[(size_t)n * 2048 + hh] = f2b(hv);

    float p[16];
    p[0]  = hv * A0.x; p[1]  = hv * A0.y; p[2]  = hv * A0.z; p[3]  = hv * A0.w;
    p[4]  = hv * A1.x; p[5]  = hv * A1.y; p[6]  = hv * A1.z; p[7]  = hv * A1.w;
    p[8]  = hv * A2.x; p[9]  = hv * A2.y; p[10] = hv * A2.z; p[11] = hv * A2.w;
    p[12] = hv * A3.x; p[13] = hv * A3.y; p[14] = hv * A3.z; p[15] = hv * A3.w;
#pragma unroll
    for (int k = 0; k < 16; ++k) {
        float v = p[k];
        v += __shfl_xor(v, 32); v += __shfl_xor(v, 16); v += __shfl_xor(v, 8);
        v += __shfl_xor(v, 4);  v += __shfl_xor(v, 2);  v += __shfl_xor(v, 1);
        p[k] = v;
    }
    const int wv = hh >> 6;
    if ((hh & 63) == 0) {
#pragma unroll
        for (int k = 0; k < 16; ++k) red[wv][k] = p[k];
    }
    __syncthreads();
    float qk[16], mx = -1e30f;
#pragma unroll
    for (int k = 0; k < 16; ++k) {
        float s = 0.f;
#pragma unroll
        for (int w2 = 0; w2 < 16; ++w2) s += red[w2][k];
        qk[k] = s * 0.03125f;             // 1/sqrt(1024)
        mx = fmaxf(mx, qk[k]);
    }
    float sum = 0.f;
#pragma unroll
    for (int k = 0; k < 16; ++k) { qk[k] = __expf(qk[k] - mx); sum += qk[k]; }
    float inv = 1.f / sum;
    float av = qk[0]*A0.x + qk[1]*A0.y + qk[2]*A0.z + qk[3]*A0.w
             + qk[4]*A1.x + qk[5]*A1.y + qk[6]*A1.z + qk[7]*A1.w
             + qk[8]*A2.x + qk[9]*A2.y + qk[10]*A2.z + qk[11]*A2.w
             + qk[12]*A3.x + qk[13]*A3.y + qk[14]*A3.z + qk[15]*A3.w;
    av *= inv;
    hattn[(size_t)n * 2048 + 1024 + hh] = f2b(av);
}

// ---------------------------------------------------------------------------
extern "C" void kernel_launch(void* const* d_in, const int* in_sizes, int n_in,
                              void* d_out, int out_size, void* d_ws, size_t ws_size,
                              hipStream_t stream) {
    const float* x     = (const float*)d_in[0];
    const float* A     = (const float*)d_in[1];
    const float* Wx    = (const float*)d_in[2];
    const float* Wh    = (const float*)d_in[3];
    const float* Wattn = (const float*)d_in[4];
    const float* b     = (const float*)d_in[5];
    float* out = (float*)d_out;

    ushort* WT    = (ushort*)d_ws;                        // 25.17 MB
    ushort* xb    = WT + (size_t)FH * KT3;                // 33.55 MB
    ushort* hattn = xb + (size_t)NB * TT * HD;            // 0.5 MB
    float*  c_buf = (float*)(hattn + (size_t)NB * 2048);  // 0.5 MB
    float*  a_prt = c_buf + (size_t)NB * HD;              // 4 or 6 slices

    const size_t base  = 25165824ull + 33554432ull + 524288ull + 524288ull;
    const size_t ap4   = 4ull  * NB * FH * 4;             // 8.39 MB
    const size_t ap6   = 6ull  * NB * FH * 4;             // 12.58 MB
    const size_t xaf32 = (size_t)TT * NB * FH * 4;        // 268.4 MB
    const size_t xab16 = xaf32 / 2;                       // 134.2 MB

    cvt_x<<<8192, 256, 0, stream>>>(x, xb);
    build_wt<<<dim3(48, 64), 256, 0, stream>>>(Wx, Wh, Wattn, WT);
    fused_kernel<0, 4, 0><<<NB, 1024, 0, stream>>>(
        a_prt, nullptr, nullptr, b, A, c_buf, hattn, out);

    if (ws_size >= base + ap4 + xaf32) {
        float* xa = (float*)((char*)d_ws + base + ap4);
        xa_gemm<1><<<dim3(32, 128), 256, 0, stream>>>(xb, WT, xa, nullptr);
        for (int t = 0; t < TT; ++t) {
            step_gemm<false><<<dim3(32, 4), 256, 0, stream>>>(nullptr, hattn, WT, a_prt);
            fused_kernel<1, 4, 2><<<NB, 1024, 0, stream>>>(
                a_prt, xa + (size_t)t * NB * FH, nullptr, b, A, c_buf, hattn,
                out + (size_t)t * HD);
        }
    } else if (ws_size >= base + ap4 + xab16) {
        ushort* xa = (ushort*)((char*)d_ws + base + ap4);
        xa_gemm<0><<<dim3(32, 128), 256, 0, stream>>>(xb, WT, nullptr, xa);
        for (int t = 0; t < TT; ++t) {
            step_gemm<false><<<dim3(32, 4), 256, 0, stream>>>(nullptr, hattn, WT, a_prt);
            fused_kernel<1, 4, 1><<<NB, 1024, 0, stream>>>(
                a_prt, nullptr, xa + (size_t)t * NB * FH, b, A, c_buf, hattn,
                out + (size_t)t * HD);
        }
    } else {
        for (int t = 0; t < TT; ++t) {
            step_gemm<true><<<dim3(32, 6), 256, 0, stream>>>(
                xb + (size_t)t * HD, hattn, WT, a_prt);
            fused_kernel<1, 6, 0><<<NB, 1024, 0, stream>>>(
                a_prt, nullptr, nullptr, b, A, c_buf, hattn,
                out + (size_t)t * HD);
        }
    }
}

// Round 7
// 2842.459 us; speedup vs baseline: 9.3189x; 1.2255x over previous
//
#include <hip/hip_runtime.h>
#include <math.h>

#define NB 128
#define TT 128
#define HD 1024
#define FH 4096

typedef __attribute__((ext_vector_type(8))) short short8v;
typedef __attribute__((ext_vector_type(4))) float float4v;

__device__ __forceinline__ ushort f2b(float f) {
    union { float f; unsigned u; } v; v.f = f;
    unsigned r = (v.u + 0x7fffu + ((v.u >> 16) & 1u)) >> 16;
    return (ushort)r;
}
__device__ __forceinline__ float b2f(ushort u) {
    union { unsigned u; float f; } v; v.u = ((unsigned)u) << 16;
    return v.f;
}
__device__ __forceinline__ float sigm(float x) { return 1.f / (1.f + __expf(-x)); }
__device__ __forceinline__ void gll16(const void* g, void* l) {
    __builtin_amdgcn_global_load_lds(
        (const __attribute__((address_space(1))) void*)g,
        (__attribute__((address_space(3))) void*)l,
        16, 0, 0);
}

// ---------------------------------------------------------------------------
// x fp32 -> bf16 ([N][T][D] preserved)
__global__ __launch_bounds__(256) void cvt_x(const float* __restrict__ x,
                                             ushort* __restrict__ xb) {
    size_t i = (size_t)blockIdx.x * 256 + threadIdx.x;
    const float4* p = (const float4*)x + i * 2;
    float4 va = p[0], vb = p[1];
    union { ushort u[8]; uint4 v; } o;
    o.u[0] = f2b(va.x); o.u[1] = f2b(va.y); o.u[2] = f2b(va.z); o.u[3] = f2b(va.w);
    o.u[4] = f2b(vb.x); o.u[5] = f2b(vb.y); o.u[6] = f2b(vb.z); o.u[7] = f2b(vb.w);
    ((uint4*)xb)[i] = o.v;
}

// ---------------------------------------------------------------------------
// Three separate transposed bf16 weight matrices:
// WT layout: [WxT (4096x1024)] [WhT (4096x1024)] [WatT (4096x1024)]
__global__ __launch_bounds__(256) void build_wt(const float* __restrict__ Wx,
                                                const float* __restrict__ Wh,
                                                const float* __restrict__ Wattn,
                                                ushort* __restrict__ WT) {
    __shared__ ushort Ls[64][65];
    int k0 = blockIdx.x * 64, n0 = blockIdx.y * 64;
    const float* W; int m;
    if (k0 < 1024)      { W = Wx;    m = 0; }
    else if (k0 < 2048) { W = Wh;    m = 1; }
    else                { W = Wattn; m = 2; }
    const int kk0 = k0 - m * 1024;
    ushort* dstm = WT + (size_t)m * FH * 1024;
    int t = threadIdx.x;
    int cc = t & 63, r4 = t >> 6;
#pragma unroll
    for (int i = 0; i < 16; ++i) {
        int r = i * 4 + r4;
        Ls[r][cc] = f2b(W[(size_t)(kk0 + r) * FH + n0 + cc]);
    }
    __syncthreads();
#pragma unroll
    for (int i = 0; i < 16; ++i) {
        int nn = i * 4 + r4;
        dstm[(size_t)(n0 + nn) * 1024 + kk0 + cc] = Ls[cc][nn];
    }
}

// ---------------------------------------------------------------------------
// XA[t][n][:] = x[n,t,:] @ Wx  (16384 x 1024 x 4096), dbuf LDS.
template <int F32OUT>
__global__ __launch_bounds__(256, 1) void xa_gemm(
    const ushort* __restrict__ xb,      // [16384][1024] rows = n*128+t
    const ushort* __restrict__ WxT,     // [4096][1024]
    float* __restrict__ xaf,
    ushort* __restrict__ xab)
{
    __shared__ ushort As[2][128 * 128];
    __shared__ ushort Bs[2][128 * 128];
    const int tid = threadIdx.x;
    const int w = tid >> 6, l = tid & 63;
    const int wm = w >> 1, wn = w & 1;
    const int lr = l & 15, g = l >> 4;
    const int n0 = blockIdx.x * 128;
    const int mt = blockIdx.y;
    const ushort* Abase = xb + (size_t)mt * 128 * 1024;
    const ushort* Bbase = WxT + (size_t)n0 * 1024;

    float4v acc[4][4];
#pragma unroll
    for (int i = 0; i < 4; ++i)
#pragma unroll
        for (int j = 0; j < 4; ++j) acc[i][j] = (float4v){0.f, 0.f, 0.f, 0.f};

    int buf = 0;
#pragma unroll
    for (int i = 0; i < 8; ++i) {
        int s = i * 256 + w * 64 + l;
        int r = s >> 4, c = (s & 8) | ((s & 7) ^ (r & 7));
        gll16(Abase + (size_t)r * 1024 + c * 8, &As[0][(i * 256 + w * 64) * 8]);
    }
#pragma unroll
    for (int i = 0; i < 8; ++i) {
        int s = i * 256 + w * 64 + l;
        int r = s >> 4, c = (s & 8) | ((s & 7) ^ (r & 7));
        gll16(Bbase + (size_t)r * 1024 + c * 8, &Bs[0][(i * 256 + w * 64) * 8]);
    }
    __syncthreads();

#pragma unroll 1
    for (int ks = 0; ks < 8; ++ks) {
        if (ks < 7) {
            const int kf = (ks + 1) * 128;
#pragma unroll
            for (int i = 0; i < 8; ++i) {
                int s = i * 256 + w * 64 + l;
                int r = s >> 4, c = (s & 8) | ((s & 7) ^ (r & 7));
                gll16(Abase + (size_t)r * 1024 + kf + c * 8,
                      &As[buf ^ 1][(i * 256 + w * 64) * 8]);
            }
#pragma unroll
            for (int i = 0; i < 8; ++i) {
                int s = i * 256 + w * 64 + l;
                int r = s >> 4, c = (s & 8) | ((s & 7) ^ (r & 7));
                gll16(Bbase + (size_t)r * 1024 + kf + c * 8,
                      &Bs[buf ^ 1][(i * 256 + w * 64) * 8]);
            }
        }
        const ushort* Ab = As[buf];
        const ushort* Bb = Bs[buf];
#pragma unroll
        for (int s4 = 0; s4 < 4; ++s4) {
            short8v af[4], bf[4];
#pragma unroll
            for (int mf = 0; mf < 4; ++mf) {
                int r = wm * 64 + mf * 16 + lr;
                int c = ((s4 * 4 + g) & 8) | (((s4 * 4 + g) & 7) ^ (r & 7));
                af[mf] = *(const short8v*)&Ab[r * 128 + c * 8];
            }
#pragma unroll
            for (int nf = 0; nf < 4; ++nf) {
                int r = wn * 64 + nf * 16 + lr;
                int c = ((s4 * 4 + g) & 8) | (((s4 * 4 + g) & 7) ^ (r & 7));
                bf[nf] = *(const short8v*)&Bb[r * 128 + c * 8];
            }
#pragma unroll
            for (int mf = 0; mf < 4; ++mf)
#pragma unroll
                for (int nf = 0; nf < 4; ++nf)
                    acc[mf][nf] = __builtin_amdgcn_mfma_f32_16x16x32_bf16(
                        af[mf], bf[nf], acc[mf][nf], 0, 0, 0);
        }
        __syncthreads();
        buf ^= 1;
    }

#pragma unroll
    for (int mf = 0; mf < 4; ++mf)
#pragma unroll
        for (int nf = 0; nf < 4; ++nf) {
            const int col = n0 + wn * 64 + nf * 16 + lr;
#pragma unroll
            for (int j = 0; j < 4; ++j) {
                const int rl = wm * 64 + mf * 16 + g * 4 + j;   // = t
                const size_t idx = ((size_t)rl * NB + mt) * FH + col;
                if (F32OUT) xaf[idx] = acc[mf][nf][j];
                else        xab[idx] = f2b(acc[mf][nf][j]);
            }
        }
}

// ---------------------------------------------------------------------------
// P2[n][j][k] = sum_h A[n][h][k] * Wattn[h][j]   (per-n 16x4096, K=1024)
// grid (16 jt, 128 n), 256 thr = 4 waves (each 16k x 64j).
__global__ __launch_bounds__(256) void p_gemm(
    const float* __restrict__ Aflat,    // [128][1024][16] f32
    const ushort* __restrict__ WatT,    // [4096][1024]
    ushort* __restrict__ P2)            // [128][4096][16] bf16
{
    __shared__ ushort ALDS[16 * 72];    // [16 k][64 h] padded to 72
    __shared__ ushort Bs[256 * 64];     // [256 j][64 h]
    const int tid = threadIdx.x;
    const int wv = tid >> 6, l = tid & 63;
    const int lr = l & 15, g = l >> 4;
    const int jt = blockIdx.x, n = blockIdx.y;

    float4v acc[4];
#pragma unroll
    for (int i = 0; i < 4; ++i) acc[i] = (float4v){0.f, 0.f, 0.f, 0.f};

#pragma unroll 1
    for (int kc = 0; kc < 16; ++kc) {
        __syncthreads();
        if (tid < 64) {
            const float* ar = Aflat + ((size_t)n * 1024 + kc * 64 + tid) * 16;
#pragma unroll
            for (int k = 0; k < 16; ++k) ALDS[k * 72 + tid] = f2b(ar[k]);
        }
#pragma unroll
        for (int i = 0; i < 8; ++i) {
            int s = i * 256 + tid;
            int r = s >> 3, c = (s & 7) ^ (r & 7);
            gll16(WatT + (size_t)(jt * 256 + r) * 1024 + kc * 64 + c * 8,
                  &Bs[(i * 256 + (tid & ~63)) * 8 + (l) * 8]);
        }
        __syncthreads();
#pragma unroll
        for (int sub = 0; sub < 2; ++sub) {
            short8v af = *(const short8v*)&ALDS[lr * 72 + sub * 32 + g * 8];
#pragma unroll
            for (int nf = 0; nf < 4; ++nf) {
                int r = wv * 64 + nf * 16 + lr;
                short8v bf = *(const short8v*)&Bs[r * 64 + (((sub * 4 + g) ^ (r & 7)) * 8)];
                acc[nf] = __builtin_amdgcn_mfma_f32_16x16x32_bf16(af, bf, acc[nf], 0, 0, 0);
            }
        }
    }

#pragma unroll
    for (int nf = 0; nf < 4; ++nf) {
        const int j = jt * 256 + wv * 64 + nf * 16 + lr;
        union { ushort u[4]; uint2 v; } o;
#pragma unroll
        for (int jj = 0; jj < 4; ++jj) o.u[jj] = f2b(acc[nf][jj]);
        *(uint2*)&P2[((size_t)n * FH + j) * 16 + g * 4] = o.v;
    }
}

// ---------------------------------------------------------------------------
// init: h0=c0=meanpool(A); qk0[n][k] = sum_h h0*A[n][h][k]; zero qk1.
__global__ __launch_bounds__(256) void init_kernel(
    const float* __restrict__ Aflat, float* __restrict__ cbuf,
    ushort* __restrict__ h0buf, float* __restrict__ qk0, float* __restrict__ qk1)
{
    __shared__ float red[4][16];
    const int n = blockIdx.x, tid = threadIdx.x;
    const int wv = tid >> 6, l = tid & 63;
    float p[16];
#pragma unroll
    for (int k = 0; k < 16; ++k) p[k] = 0.f;
#pragma unroll
    for (int u = 0; u < 4; ++u) {
        const int h = tid + u * 256;
        const float4* a4 = (const float4*)(Aflat + ((size_t)n * 1024 + h) * 16);
        float ar[16];
#pragma unroll
        for (int q = 0; q < 4; ++q) {
            float4 v = a4[q];
            ar[q*4+0]=v.x; ar[q*4+1]=v.y; ar[q*4+2]=v.z; ar[q*4+3]=v.w;
        }
        float s = 0.f;
#pragma unroll
        for (int k = 0; k < 16; ++k) s += ar[k];
        float hv = s * 0.0625f;
        cbuf[(size_t)n * 1024 + h] = hv;
        h0buf[(size_t)n * 1024 + h] = f2b(hv);
#pragma unroll
        for (int k = 0; k < 16; ++k) p[k] += hv * ar[k];
    }
#pragma unroll
    for (int k = 0; k < 16; ++k) {
        float v = p[k];
        v += __shfl_xor(v, 32); v += __shfl_xor(v, 16); v += __shfl_xor(v, 8);
        v += __shfl_xor(v, 4);  v += __shfl_xor(v, 2);  v += __shfl_xor(v, 1);
        p[k] = v;
    }
    if (l == 0) {
#pragma unroll
        for (int k = 0; k < 16; ++k) red[wv][k] = p[k];
    }
    __syncthreads();
    if (tid < 16) {
        qk0[n * 16 + tid] = red[0][tid] + red[1][tid] + red[2][tid] + red[3][tid];
        qk1[n * 16 + tid] = 0.f;
    }
}

// ---------------------------------------------------------------------------
// ONE kernel per step. XAF: 2 fp32 XA, 1 bf16 XA, 0 full-K (x in K-loop).
// grid (64 bx, 2 my), 256 thr = 4 waves. Block: M=64 n, N=64 cols
// (4 gate-quarters x 16 h-cols), K=1024 (or 2048 FULLK), BK=64 dbuf.
template <int XAF>
__global__ __launch_bounds__(256) void step_kernel(
    const ushort* __restrict__ hcur,    // [128][1024] bf16
    ushort* __restrict__ hnext,
    const ushort* __restrict__ xb_t,    // FULLK: + t*HD, row stride TT*HD
    const ushort* __restrict__ WxT,     // [4096][1024]
    const ushort* __restrict__ WhT,     // [4096][1024]
    const ushort* __restrict__ P2,      // [128][4096][16]
    const float* __restrict__ xaf_t,    // XAF=2
    const ushort* __restrict__ xab_t,   // XAF=1
    const float* __restrict__ bias,
    const float* __restrict__ Aflat,    // [128][1024][16]
    float* __restrict__ cbuf,
    const float* __restrict__ qk_cur,
    float* __restrict__ qk_next,
    float* __restrict__ qk_zero,
    float* __restrict__ out_t)          // + t*HD, row stride TT*HD
{
    __shared__ ushort As[2][64 * 64];
    __shared__ ushort Bs[2][64 * 64];
    __shared__ float wLDS[64][16];
    const int tid = threadIdx.x;
    const int w = tid >> 6, l = tid & 63;
    const int lr = l & 15, g = l >> 4;
    const int bx = blockIdx.x;
    const int nbase = blockIdx.y * 64;
    const int NK = (XAF == 0) ? 32 : 16;

    // zero the t+2 qk buffer (redundant same-value writes across blocks: benign)
    for (int i = tid; i < 2048; i += 256) qk_zero[i] = 0.f;

    // softmax(qk_cur * 1/32) for our 64 n rows
    if (tid < 64) {
        const float* q = qk_cur + (nbase + tid) * 16;
        float s[16], m = -1e30f;
#pragma unroll
        for (int k = 0; k < 16; ++k) { s[k] = q[k] * 0.03125f; m = fmaxf(m, s[k]); }
        float sum = 0.f;
#pragma unroll
        for (int k = 0; k < 16; ++k) { s[k] = __expf(s[k] - m); sum += s[k]; }
        float inv = 1.f / sum;
#pragma unroll
        for (int k = 0; k < 16; ++k) wLDS[tid][k] = s[k] * inv;
    }

#define STAGE(b, kc)                                                           \
    do {                                                                       \
        const int koff = (kc) * 64;                                            \
        _Pragma("unroll")                                                      \
        for (int i = 0; i < 2; ++i) {                                          \
            int s = i * 256 + tid;                                             \
            int r = s >> 3, c = (s & 7) ^ (r & 7);                             \
            const ushort* src;                                                 \
            if (XAF == 0 && koff < 1024)                                       \
                src = xb_t + (size_t)(nbase + r) * (TT * HD) + koff + c * 8;   \
            else {                                                             \
                int kh = (XAF == 0) ? koff - 1024 : koff;                      \
                src = hcur + (size_t)(nbase + r) * 1024 + kh + c * 8;          \
            }                                                                  \
            gll16(src, &As[b][s * 8]);                                         \
        }                                                                      \
        _Pragma("unroll")                                                      \
        for (int i = 0; i < 2; ++i) {                                          \
            int s = i * 256 + tid;                                             \
            int r = s >> 3, c = (s & 7) ^ (r & 7);                             \
            const int jg = (r >> 4) * 1024 + bx * 16 + (r & 15);               \
            const ushort* src;                                                 \
            if (XAF == 0 && koff < 1024)                                       \
                src = WxT + (size_t)jg * 1024 + koff + c * 8;                  \
            else {                                                             \
                int kh = (XAF == 0) ? koff - 1024 : koff;                      \
                src = WhT + (size_t)jg * 1024 + kh + c * 8;                    \
            }                                                                  \
            gll16(src, &Bs[b][s * 8]);                                         \
        }                                                                      \
    } while (0)

    float4v acc[4];
#pragma unroll
    for (int i = 0; i < 4; ++i) acc[i] = (float4v){0.f, 0.f, 0.f, 0.f};

    STAGE(0, 0);
    __syncthreads();
    int buf = 0;
#pragma unroll 1
    for (int kc = 0; kc < NK; ++kc) {
        if (kc + 1 < NK) STAGE(buf ^ 1, kc + 1);
        const ushort* Ab = As[buf];
        const ushort* Bb = Bs[buf];
#pragma unroll
        for (int sub = 0; sub < 2; ++sub) {
            const int ra = w * 16 + lr;
            short8v af = *(const short8v*)&Ab[ra * 64 + (((sub * 4 + g) ^ (ra & 7)) * 8)];
#pragma unroll
            for (int nf = 0; nf < 4; ++nf) {
                const int rb = nf * 16 + lr;
                short8v bf = *(const short8v*)&Bb[rb * 64 + (((sub * 4 + g) ^ (rb & 7)) * 8)];
                acc[nf] = __builtin_amdgcn_mfma_f32_16x16x32_bf16(af, bf, acc[nf], 0, 0, 0);
            }
        }
        __syncthreads();
        buf ^= 1;
    }
#undef STAGE

    // ---- epilogue: gates + cell + h/out + qk-partials ----
    const int hc = bx * 16 + lr;
    const int kmap = ((lr & 1) << 3) | ((lr & 2) << 1) | ((lr & 4) >> 1) | ((lr & 8) >> 3);

#pragma unroll
    for (int j = 0; j < 4; ++j) {
        const int n_l = w * 16 + g * 4 + j;
        const int n = nbase + n_l;
        float wv_[16];
#pragma unroll
        for (int k = 0; k < 16; ++k) wv_[k] = wLDS[n_l][k];

        float val[4];
#pragma unroll
        for (int nf = 0; nf < 4; ++nf) {
            const int jg = nf * 1024 + hc;
            float v = acc[nf][j] + bias[jg];
            if (XAF == 2) v += xaf_t[(size_t)n * FH + jg];
            else if (XAF == 1) v += b2f(xab_t[(size_t)n * FH + jg]);
            const ushort* pp = P2 + ((size_t)n * FH + jg) * 16;
            const uint4 pv0 = *(const uint4*)pp;
            const uint4 pv1 = *(const uint4*)(pp + 8);
            const uint pw[8] = {pv0.x, pv0.y, pv0.z, pv0.w, pv1.x, pv1.y, pv1.z, pv1.w};
#pragma unroll
            for (int k2 = 0; k2 < 8; ++k2) {
                v += wv_[k2 * 2]     * b2f((ushort)(pw[k2] & 0xffff));
                v += wv_[k2 * 2 + 1] * b2f((ushort)(pw[k2] >> 16));
            }
            val[nf] = v;
        }

        const size_t chidx = (size_t)n * 1024 + hc;
        float cn = sigm(val[1]) * cbuf[chidx] + sigm(val[0]) * tanhf(val[3]);
        float hv = sigm(val[2]) * tanhf(cn);
        cbuf[chidx] = cn;
        out_t[(size_t)n * (TT * HD) + hc] = hv;
        hnext[chidx] = f2b(hv);

        // qk partial: p[k] = hv * A[n][hc][k]; reduce over hc (lr) in 16-lane grp
        const float4* a4 = (const float4*)(Aflat + chidx * 16);
        float vv[16];
#pragma unroll
        for (int q = 0; q < 4; ++q) {
            float4 av = a4[q];
            vv[q*4+0] = hv * av.x; vv[q*4+1] = hv * av.y;
            vv[q*4+2] = hv * av.z; vv[q*4+3] = hv * av.w;
        }
        {   // segmented butterfly: 16 values over 16 lanes
            bool hi = (lr & 1);
#pragma unroll
            for (int q = 0; q < 8; ++q) {
                float send = hi ? vv[q] : vv[q + 8];
                float recv = __shfl_xor(send, 1);
                vv[q] = (hi ? vv[q + 8] : vv[q]) + recv;
            }
            hi = (lr & 2);
#pragma unroll
            for (int q = 0; q < 4; ++q) {
                float send = hi ? vv[q] : vv[q + 4];
                float recv = __shfl_xor(send, 2);
                vv[q] = (hi ? vv[q + 4] : vv[q]) + recv;
            }
            hi = (lr & 4);
#pragma unroll
            for (int q = 0; q < 2; ++q) {
                float send = hi ? vv[q] : vv[q + 2];
                float recv = __shfl_xor(send, 4);
                vv[q] = (hi ? vv[q + 2] : vv[q]) + recv;
            }
            hi = (lr & 8);
            {
                float send = hi ? vv[0] : vv[1];
                float recv = __shfl_xor(send, 8);
                vv[0] = (hi ? vv[1] : vv[0]) + recv;
            }
        }
        atomicAdd(&qk_next[n * 16 + kmap], vv[0]);
    }
}

// ---------------------------------------------------------------------------
extern "C" void kernel_launch(void* const* d_in, const int* in_sizes, int n_in,
                              void* d_out, int out_size, void* d_ws, size_t ws_size,
                              hipStream_t stream) {
    const float* x     = (const float*)d_in[0];
    const float* A     = (const float*)d_in[1];
    const float* Wx    = (const float*)d_in[2];
    const float* Wh    = (const float*)d_in[3];
    const float* Wattn = (const float*)d_in[4];
    const float* b     = (const float*)d_in[5];
    float* out = (float*)d_out;

    ushort* WT  = (ushort*)d_ws;                       // 3 x 8.39 MB
    ushort* WxT = WT;
    ushort* WhT = WT + (size_t)FH * 1024;
    ushort* WatT= WT + (size_t)2 * FH * 1024;
    ushort* xb  = WT + (size_t)3 * FH * 1024;          // 33.55 MB
    ushort* hb  = xb + (size_t)NB * TT * HD;           // 2 x 0.26 MB
    float*  cb  = (float*)(hb + (size_t)2 * NB * HD);  // 0.52 MB
    float*  qk  = cb + (size_t)NB * HD;                // 3 x 8 KB
    char*   tail = (char*)(qk + 3 * 2048);

    const size_t base  = (size_t)(tail - (char*)d_ws);
    const size_t xaf32 = (size_t)TT * NB * FH * 4;     // 268.4 MB
    const size_t xab16 = xaf32 / 2;                    // 134.2 MB
    const size_t p2sz  = (size_t)NB * FH * 16 * 2;     // 16.8 MB

    cvt_x<<<8192, 256, 0, stream>>>(x, xb);
    build_wt<<<dim3(48, 64), 256, 0, stream>>>(Wx, Wh, Wattn, WT);
    init_kernel<<<NB, 256, 0, stream>>>(A, cb, hb, qk, qk + 2048);

    int xafmode;
    float* xaf = nullptr; ushort* xab = nullptr; ushort* P2;
    if (ws_size >= base + xaf32) {
        xafmode = 2;
        xaf = (float*)tail;
        P2 = xb;                                       // overlay (xb dead after xa_gemm)
        xa_gemm<1><<<dim3(32, 128), 256, 0, stream>>>(xb, WxT, xaf, nullptr);
    } else if (ws_size >= base + xab16) {
        xafmode = 1;
        xab = (ushort*)tail;
        P2 = xb;
        xa_gemm<0><<<dim3(32, 128), 256, 0, stream>>>(xb, WxT, nullptr, xab);
    } else {
        xafmode = 0;
        P2 = (ushort*)tail;                            // xb stays live (FULLK)
    }
    p_gemm<<<dim3(16, NB), 256, 0, stream>>>(A, WatT, P2);

    for (int t = 0; t < TT; ++t) {
        const ushort* hc = hb + (size_t)(t & 1) * NB * HD;
        ushort* hn       = hb + (size_t)((t + 1) & 1) * NB * HD;
        const float* qc  = qk + (size_t)(t % 3) * 2048;
        float* qn        = qk + (size_t)((t + 1) % 3) * 2048;
        float* qz        = qk + (size_t)((t + 2) % 3) * 2048;
        if (xafmode == 2)
            step_kernel<2><<<dim3(64, 2), 256, 0, stream>>>(
                hc, hn, xb + (size_t)t * HD, WxT, WhT, P2,
                xaf + (size_t)t * NB * FH, nullptr, b, A, cb, qc, qn, qz,
                out + (size_t)t * HD);
        else if (xafmode == 1)
            step_kernel<1><<<dim3(64, 2), 256, 0, stream>>>(
                hc, hn, xb + (size_t)t * HD, WxT, WhT, P2,
                nullptr, xab + (size_t)t * NB * FH, b, A, cb, qc, qn, qz,
                out + (size_t)t * HD);
        else
            step_kernel<0><<<dim3(64, 2), 256, 0, stream>>>(
                hc, hn, xb + (size_t)t * HD, WxT, WhT, P2,
                nullptr, nullptr, b, A, cb, qc, qn, qz,
                out + (size_t)t * HD);
    }
}

// Round 8
// 2518.883 us; speedup vs baseline: 10.5160x; 1.1285x over previous
//
#include <hip/hip_runtime.h>
#include <math.h>

#define NB 128
#define TT 128
#define HD 1024
#define FH 4096

typedef __attribute__((ext_vector_type(8))) short short8v;
typedef __attribute__((ext_vector_type(4))) float float4v;

__device__ __forceinline__ ushort f2b(float f) {
    union { float f; unsigned u; } v; v.f = f;
    unsigned r = (v.u + 0x7fffu + ((v.u >> 16) & 1u)) >> 16;
    return (ushort)r;
}
__device__ __forceinline__ float b2f(ushort u) {
    union { unsigned u; float f; } v; v.u = ((unsigned)u) << 16;
    return v.f;
}
__device__ __forceinline__ float sigm(float x) { return 1.f / (1.f + __expf(-x)); }
__device__ __forceinline__ void gll16(const void* g, void* l) {
    __builtin_amdgcn_global_load_lds(
        (const __attribute__((address_space(1))) void*)g,
        (__attribute__((address_space(3))) void*)l,
        16, 0, 0);
}
// XOR chunk swizzle within a 16-chunk (256B) row; involution in low 3 bits.
__device__ __forceinline__ int swz(int c, int r) {
    return (c & 8) | ((c & 7) ^ (r & 7));
}

// ---------------------------------------------------------------------------
// x fp32 -> bf16 ([N][T][D] preserved)
__global__ __launch_bounds__(256) void cvt_x(const float* __restrict__ x,
                                             ushort* __restrict__ xb) {
    size_t i = (size_t)blockIdx.x * 256 + threadIdx.x;
    const float4* p = (const float4*)x + i * 2;
    float4 va = p[0], vb = p[1];
    union { ushort u[8]; uint4 v; } o;
    o.u[0] = f2b(va.x); o.u[1] = f2b(va.y); o.u[2] = f2b(va.z); o.u[3] = f2b(va.w);
    o.u[4] = f2b(vb.x); o.u[5] = f2b(vb.y); o.u[6] = f2b(vb.z); o.u[7] = f2b(vb.w);
    ((uint4*)xb)[i] = o.v;
}

// ---------------------------------------------------------------------------
// WT layout: [WxT (4096x1024)] [WhT (4096x1024)] [WatT (4096x1024)], bf16.
__global__ __launch_bounds__(256) void build_wt(const float* __restrict__ Wx,
                                                const float* __restrict__ Wh,
                                                const float* __restrict__ Wattn,
                                                ushort* __restrict__ WT) {
    __shared__ ushort Ls[64][65];
    int k0 = blockIdx.x * 64, n0 = blockIdx.y * 64;
    const float* W; int m;
    if (k0 < 1024)      { W = Wx;    m = 0; }
    else if (k0 < 2048) { W = Wh;    m = 1; }
    else                { W = Wattn; m = 2; }
    const int kk0 = k0 - m * 1024;
    ushort* dstm = WT + (size_t)m * FH * 1024;
    int t = threadIdx.x;
    int cc = t & 63, r4 = t >> 6;
#pragma unroll
    for (int i = 0; i < 16; ++i) {
        int r = i * 4 + r4;
        Ls[r][cc] = f2b(W[(size_t)(kk0 + r) * FH + n0 + cc]);
    }
    __syncthreads();
#pragma unroll
    for (int i = 0; i < 16; ++i) {
        int nn = i * 4 + r4;
        dstm[(size_t)(n0 + nn) * 1024 + kk0 + cc] = Ls[cc][nn];
    }
}

// ---------------------------------------------------------------------------
// init: h0=c0=meanpool(A); Ab16 = bf16(A); qk0[n][k] = sum_h h0*A; zero qk1.
__global__ __launch_bounds__(256) void init_kernel(
    const float* __restrict__ Aflat, float* __restrict__ cbuf,
    ushort* __restrict__ h0buf, ushort* __restrict__ Ab16,
    float* __restrict__ qk0, float* __restrict__ qk1)
{
    __shared__ float red[4][16];
    const int n = blockIdx.x, tid = threadIdx.x;
    const int wv = tid >> 6, l = tid & 63;
    float p[16];
#pragma unroll
    for (int k = 0; k < 16; ++k) p[k] = 0.f;
#pragma unroll
    for (int u = 0; u < 4; ++u) {
        const int h = tid + u * 256;
        const size_t idx = (size_t)n * 1024 + h;
        const float4* a4 = (const float4*)(Aflat + idx * 16);
        float ar[16];
#pragma unroll
        for (int q = 0; q < 4; ++q) {
            float4 v = a4[q];
            ar[q*4+0]=v.x; ar[q*4+1]=v.y; ar[q*4+2]=v.z; ar[q*4+3]=v.w;
        }
        union { ushort us[16]; uint4 v[2]; } ob;
#pragma unroll
        for (int k = 0; k < 16; ++k) ob.us[k] = f2b(ar[k]);
        uint4* dst = (uint4*)(Ab16 + idx * 16);
        dst[0] = ob.v[0]; dst[1] = ob.v[1];

        float s = 0.f;
#pragma unroll
        for (int k = 0; k < 16; ++k) s += ar[k];
        float hv = s * 0.0625f;
        cbuf[idx] = hv;
        h0buf[idx] = f2b(hv);
#pragma unroll
        for (int k = 0; k < 16; ++k) p[k] += hv * ar[k];
    }
#pragma unroll
    for (int k = 0; k < 16; ++k) {
        float v = p[k];
        v += __shfl_xor(v, 32); v += __shfl_xor(v, 16); v += __shfl_xor(v, 8);
        v += __shfl_xor(v, 4);  v += __shfl_xor(v, 2);  v += __shfl_xor(v, 1);
        p[k] = v;
    }
    if (l == 0) {
#pragma unroll
        for (int k = 0; k < 16; ++k) red[wv][k] = p[k];
    }
    __syncthreads();
    if (tid < 16) {
        qk0[n * 16 + tid] = red[0][tid] + red[1][tid] + red[2][tid] + red[3][tid];
        qk1[n * 16 + tid] = 0.f;
    }
}

// ---------------------------------------------------------------------------
// P2[n][j][k] = sum_h A[n][h][k] * Wattn[h][j]; 4-n batched per block.
// grid (16 jt, 32 ng), 256 thr = 4 waves (each 16k x 64j, 4 n slices).
__global__ __launch_bounds__(256) void p_gemm(
    const ushort* __restrict__ Ab16,    // [128][1024][16]
    const ushort* __restrict__ WatT,    // [4096][1024]
    ushort* __restrict__ P2)            // [128][4096][16] bf16
{
    __shared__ ushort ALDS[4 * 16 * 72];
    __shared__ ushort Bs[256 * 64];
    const int tid = threadIdx.x;
    const int wv = tid >> 6, l = tid & 63;
    const int lr = l & 15, g = l >> 4;
    const int jt = blockIdx.x, n0 = blockIdx.y * 4;
    const int snn = tid >> 6, shl = tid & 63;

    float4v acc[4][4];
#pragma unroll
    for (int i = 0; i < 4; ++i)
#pragma unroll
        for (int j = 0; j < 4; ++j) acc[i][j] = (float4v){0.f, 0.f, 0.f, 0.f};

#pragma unroll 1
    for (int kc = 0; kc < 16; ++kc) {
        __syncthreads();
        {   // A stage: thread handles one (nn, h)
            const ushort* src = Ab16 + ((size_t)(n0 + snn) * 1024 + kc * 64 + shl) * 16;
            union { uint4 v[2]; ushort us[16]; } iv;
            iv.v[0] = *(const uint4*)src;
            iv.v[1] = *(const uint4*)(src + 8);
#pragma unroll
            for (int k = 0; k < 16; ++k)
                ALDS[(snn * 16 + k) * 72 + shl] = iv.us[k];
        }
#pragma unroll
        for (int i = 0; i < 8; ++i) {   // B stage
            int s = i * 256 + tid;
            int r = s >> 3, c = (s & 7) ^ (r & 7);
            gll16(WatT + (size_t)(jt * 256 + r) * 1024 + kc * 64 + c * 8,
                  &Bs[s * 8]);
        }
        __syncthreads();
#pragma unroll
        for (int sub = 0; sub < 2; ++sub) {
            short8v af[4], bf[4];
#pragma unroll
            for (int nn = 0; nn < 4; ++nn)
                af[nn] = *(const short8v*)&ALDS[(nn * 16 + lr) * 72 + sub * 32 + g * 8];
#pragma unroll
            for (int nf = 0; nf < 4; ++nf) {
                int rb = wv * 64 + nf * 16 + lr;
                bf[nf] = *(const short8v*)&Bs[rb * 64 + (((sub * 4 + g) ^ (rb & 7)) * 8)];
            }
#pragma unroll
            for (int nn = 0; nn < 4; ++nn)
#pragma unroll
                for (int nf = 0; nf < 4; ++nf)
                    acc[nn][nf] = __builtin_amdgcn_mfma_f32_16x16x32_bf16(
                        af[nn], bf[nf], acc[nn][nf], 0, 0, 0);
        }
    }

#pragma unroll
    for (int nn = 0; nn < 4; ++nn)
#pragma unroll
        for (int nf = 0; nf < 4; ++nf) {
            const int j = jt * 256 + wv * 64 + nf * 16 + lr;
            union { ushort u[4]; uint2 v; } o;
#pragma unroll
            for (int jj = 0; jj < 4; ++jj) o.u[jj] = f2b(acc[nn][nf][jj]);
            *(uint2*)&P2[((size_t)(n0 + nn) * FH + j) * 16 + g * 4] = o.v;
        }
}

// ---------------------------------------------------------------------------
// Per-step kernel v2: 512 blocks (2/CU), 256 thr = 4 waves (2 mh x 2 kh).
// Block: 32n x 32j (8 hc x 4 gates), K = 2048 = [x_t | h], BK=128 dbuf.
// kh0 waves: x_t @ WxT over K 0..1023; kh1: h @ WhT. LDS combine, then
// per-thread (n,hc) epilogue: gates, cell, out, qk butterfly + atomics.
__global__ __launch_bounds__(256) void step_kernel(
    const ushort* __restrict__ hcur,    // [128][1024] bf16
    ushort* __restrict__ hnext,
    const ushort* __restrict__ xb_t,    // + t*HD, row stride TT*HD
    const ushort* __restrict__ WxT,     // [4096][1024]
    const ushort* __restrict__ WhT,     // [4096][1024]
    const ushort* __restrict__ P2,      // [128][4096][16]
    const ushort* __restrict__ Ab16,    // [128][1024][16]
    const float* __restrict__ bias,
    float* __restrict__ cbuf,
    const float* __restrict__ qk_cur,
    float* __restrict__ qk_next,
    float* __restrict__ qk_zero,
    float* __restrict__ out_t)          // + t*HD, row stride TT*HD
{
    __shared__ ushort AS[16384];        // 2 buf x 2 kh x 32n x 16 units x 8
    __shared__ ushort BS[16384];
    __shared__ float accL[2 * 32 * 33];
    __shared__ float wLDS[32 * 16];

    const int tid = threadIdx.x;
    const int w = tid >> 6, l = tid & 63;
    const int mh = w & 1, kh = w >> 1;
    const int lr = l & 15, g = l >> 4;

    // XCD-chunked swizzle: each XCD owns 16 contiguous bx groups.
    const int bid = blockIdx.x;
    const int xcd = bid & 7, ii = bid >> 3;
    const int bx = xcd * 16 + (ii & 15);
    const int my = ii >> 4;
    const int n0 = my * 32;

    if (bid < 8) qk_zero[bid * 256 + tid] = 0.f;

    if (tid < 32) {   // softmax(qk/32) for this block's 32 n rows
        const float* q = qk_cur + (n0 + tid) * 16;
        float s[16], m = -1e30f;
#pragma unroll
        for (int k = 0; k < 16; ++k) { s[k] = q[k] * 0.03125f; m = fmaxf(m, s[k]); }
        float sum = 0.f;
#pragma unroll
        for (int k = 0; k < 16; ++k) { s[k] = __expf(s[k] - m); sum += s[k]; }
        float inv = 1.f / sum;
#pragma unroll
        for (int k = 0; k < 16; ++k) wLDS[tid * 16 + k] = s[k] * inv;
    }

#define STAGE(b, kc)                                                           \
    do {                                                                       \
        _Pragma("unroll")                                                      \
        for (int i = 0; i < 4; ++i) {                                          \
            int u = i * 256 + tid;                                             \
            int skh = u >> 9, rem = u & 511;                                   \
            int r = rem >> 4, c = rem & 15;                                    \
            int lc = swz(c, r);                                                \
            const ushort* src = skh                                            \
                ? hcur + (size_t)(n0 + r) * 1024 + (kc) * 128 + lc * 8         \
                : xb_t + (size_t)(n0 + r) * (TT * HD) + (kc) * 128 + lc * 8;   \
            gll16(src, AS + (((b) * 2 + skh) * 512 + rem) * 8);                \
        }                                                                      \
        _Pragma("unroll")                                                      \
        for (int i = 0; i < 4; ++i) {                                          \
            int u = i * 256 + tid;                                             \
            int skh = u >> 9, rem = u & 511;                                   \
            int r = rem >> 4, c = rem & 15;                                    \
            int lc = swz(c, r);                                                \
            int jg = (r >> 3) * 1024 + bx * 8 + (r & 7);                       \
            const ushort* src = (skh ? WhT : WxT) + (size_t)jg * 1024          \
                                + (kc) * 128 + lc * 8;                         \
            gll16(src, BS + (((b) * 2 + skh) * 512 + rem) * 8);                \
        }                                                                      \
    } while (0)

    float4v acc[2];
    acc[0] = (float4v){0.f, 0.f, 0.f, 0.f};
    acc[1] = (float4v){0.f, 0.f, 0.f, 0.f};

    STAGE(0, 0);
    __syncthreads();
    int buf = 0;
#pragma unroll 1
    for (int kc = 0; kc < 8; ++kc) {
        if (kc < 7) STAGE(buf ^ 1, kc + 1);
        const int base = (buf * 2 + kh) * 512;
        const int ra = mh * 16 + lr;
#pragma unroll
        for (int ks = 0; ks < 4; ++ks) {
            const int c = ks * 4 + g;
            short8v af = *(const short8v*)&AS[(base + ra * 16 + swz(c, ra)) * 8];
#pragma unroll
            for (int nf = 0; nf < 2; ++nf) {
                const int rb = nf * 16 + lr;
                short8v bf = *(const short8v*)&BS[(base + rb * 16 + swz(c, rb)) * 8];
                acc[nf] = __builtin_amdgcn_mfma_f32_16x16x32_bf16(af, bf, acc[nf], 0, 0, 0);
            }
        }
        __syncthreads();
        buf ^= 1;
    }
#undef STAGE

    // combine K-halves via LDS
#pragma unroll
    for (int nf = 0; nf < 2; ++nf)
#pragma unroll
        for (int jj = 0; jj < 4; ++jj)
            accL[(kh * 32 + mh * 16 + g * 4 + jj) * 33 + nf * 16 + lr] = acc[nf][jj];
    __syncthreads();

    // ---- epilogue: thread = one (n, hc) cell ----
    const int n_l = tid >> 3, hcl = tid & 7;
    const int n = n0 + n_l;
    const int hc = bx * 8 + hcl;

    float wv_[16];
#pragma unroll
    for (int k = 0; k < 16; ++k) wv_[k] = wLDS[n_l * 16 + k];

    float val[4];
#pragma unroll
    for (int q = 0; q < 4; ++q) {
        const int cq = q * 8 + hcl;
        float v = accL[n_l * 33 + cq] + accL[(32 + n_l) * 33 + cq]
                + bias[q * 1024 + hc];
        const ushort* pp = P2 + ((size_t)n * FH + q * 1024 + hc) * 16;
        union { uint4 v[2]; ushort us[16]; } pv;
        pv.v[0] = *(const uint4*)pp;
        pv.v[1] = *(const uint4*)(pp + 8);
#pragma unroll
        for (int k = 0; k < 16; ++k) v += wv_[k] * b2f(pv.us[k]);
        val[q] = v;
    }

    const size_t chidx = (size_t)n * 1024 + hc;
    float cn = sigm(val[1]) * cbuf[chidx] + sigm(val[0]) * tanhf(val[3]);
    float hv = sigm(val[2]) * tanhf(cn);
    cbuf[chidx] = cn;
    out_t[(size_t)n * (TT * HD) + hc] = hv;
    hnext[chidx] = f2b(hv);

    // qk partials: p[k] = hv * A[n][hc][k], reduced over 8 hcl lanes
    union { uint4 v[2]; ushort us[16]; } av;
    {
        const ushort* ap = Ab16 + chidx * 16;
        av.v[0] = *(const uint4*)ap;
        av.v[1] = *(const uint4*)(ap + 8);
    }
    float vv[16];
#pragma unroll
    for (int k = 0; k < 16; ++k) vv[k] = hv * b2f(av.us[k]);
    {
        bool hi = (hcl & 1);
#pragma unroll
        for (int q = 0; q < 8; ++q) {
            float send = hi ? vv[q] : vv[q + 8];
            float recv = __shfl_xor(send, 1);
            vv[q] = (hi ? vv[q + 8] : vv[q]) + recv;
        }
        hi = (hcl & 2);
#pragma unroll
        for (int q = 0; q < 4; ++q) {
            float send = hi ? vv[q] : vv[q + 4];
            float recv = __shfl_xor(send, 2);
            vv[q] = (hi ? vv[q + 4] : vv[q]) + recv;
        }
        hi = (hcl & 4);
#pragma unroll
        for (int q = 0; q < 2; ++q) {
            float send = hi ? vv[q] : vv[q + 2];
            float recv = __shfl_xor(send, 4);
            vv[q] = (hi ? vv[q + 2] : vv[q]) + recv;
        }
    }
    const int kbase = ((hcl & 1) << 3) | ((hcl & 2) << 1) | ((hcl & 4) >> 1);
    atomicAdd(&qk_next[n * 16 + kbase],     vv[0]);
    atomicAdd(&qk_next[n * 16 + kbase + 1], vv[1]);
}

// ---------------------------------------------------------------------------
extern "C" void kernel_launch(void* const* d_in, const int* in_sizes, int n_in,
                              void* d_out, int out_size, void* d_ws, size_t ws_size,
                              hipStream_t stream) {
    const float* x     = (const float*)d_in[0];
    const float* A     = (const float*)d_in[1];
    const float* Wx    = (const float*)d_in[2];
    const float* Wh    = (const float*)d_in[3];
    const float* Wattn = (const float*)d_in[4];
    const float* b     = (const float*)d_in[5];
    float* out = (float*)d_out;

    ushort* WT   = (ushort*)d_ws;                          // 3 x 8.39 MB
    ushort* WxT  = WT;
    ushort* WhT  = WT + (size_t)FH * 1024;
    ushort* WatT = WT + (size_t)2 * FH * 1024;
    ushort* xb   = WT + (size_t)3 * FH * 1024;             // 33.55 MB
    ushort* Ab16 = xb + (size_t)NB * TT * HD;              // 4.19 MB
    ushort* hb   = Ab16 + (size_t)NB * HD * 16;            // 2 x 0.26 MB
    float*  cb   = (float*)(hb + (size_t)2 * NB * HD);     // 0.52 MB
    float*  qk   = cb + (size_t)NB * HD;                   // 3 x 8 KB
    ushort* P2   = (ushort*)(qk + 3 * 2048);               // 16.78 MB

    cvt_x<<<8192, 256, 0, stream>>>(x, xb);
    build_wt<<<dim3(48, 64), 256, 0, stream>>>(Wx, Wh, Wattn, WT);
    init_kernel<<<NB, 256, 0, stream>>>(A, cb, hb, Ab16, qk, qk + 2048);
    p_gemm<<<dim3(16, 32), 256, 0, stream>>>(Ab16, WatT, P2);

    for (int t = 0; t < TT; ++t) {
        const ushort* hc = hb + (size_t)(t & 1) * NB * HD;
        ushort* hn       = hb + (size_t)((t + 1) & 1) * NB * HD;
        const float* qc  = qk + (size_t)(t % 3) * 2048;
        float* qn        = qk + (size_t)((t + 1) % 3) * 2048;
        float* qz        = qk + (size_t)((t + 2) % 3) * 2048;
        step_kernel<<<512, 256, 0, stream>>>(
            hc, hn, xb + (size_t)t * HD, WxT, WhT, P2, Ab16, b, cb,
            qc, qn, qz, out + (size_t)t * HD);
    }
}

// Round 9
// 2046.065 us; speedup vs baseline: 12.9461x; 1.2311x over previous
//
#include <hip/hip_runtime.h>
#include <math.h>

#define NB 128
#define TT 128
#define HD 1024
#define FH 4096
#define QB 16            // qk contention-spread buckets
#define QSLOT (QB * 2048)

typedef __attribute__((ext_vector_type(8))) short short8v;
typedef __attribute__((ext_vector_type(4))) float float4v;

__device__ __forceinline__ ushort f2b(float f) {
    union { float f; unsigned u; } v; v.f = f;
    unsigned r = (v.u + 0x7fffu + ((v.u >> 16) & 1u)) >> 16;
    return (ushort)r;
}
__device__ __forceinline__ float b2f(ushort u) {
    union { unsigned u; float f; } v; v.u = ((unsigned)u) << 16;
    return v.f;
}
__device__ __forceinline__ float sigm(float x) { return 1.f / (1.f + __expf(-x)); }
__device__ __forceinline__ void gll16(const void* g, void* l) {
    __builtin_amdgcn_global_load_lds(
        (const __attribute__((address_space(1))) void*)g,
        (__attribute__((address_space(3))) void*)l,
        16, 0, 0);
}
// XOR chunk swizzle within a 16-chunk (256B) row; involution in low 3 bits.
__device__ __forceinline__ int swz(int c, int r) {
    return (c & 8) | ((c & 7) ^ (r & 7));
}

// ---------------------------------------------------------------------------
// x fp32 -> bf16 ([N][T][D] preserved)
__global__ __launch_bounds__(256) void cvt_x(const float* __restrict__ x,
                                             ushort* __restrict__ xb) {
    size_t i = (size_t)blockIdx.x * 256 + threadIdx.x;
    const float4* p = (const float4*)x + i * 2;
    float4 va = p[0], vb = p[1];
    union { ushort u[8]; uint4 v; } o;
    o.u[0] = f2b(va.x); o.u[1] = f2b(va.y); o.u[2] = f2b(va.z); o.u[3] = f2b(va.w);
    o.u[4] = f2b(vb.x); o.u[5] = f2b(vb.y); o.u[6] = f2b(vb.z); o.u[7] = f2b(vb.w);
    ((uint4*)xb)[i] = o.v;
}

// ---------------------------------------------------------------------------
// WT layout: [WxT (4096x1024)] [WhT (4096x1024)] [WatT (4096x1024)], bf16.
__global__ __launch_bounds__(256) void build_wt(const float* __restrict__ Wx,
                                                const float* __restrict__ Wh,
                                                const float* __restrict__ Wattn,
                                                ushort* __restrict__ WT) {
    __shared__ ushort Ls[64][65];
    int k0 = blockIdx.x * 64, n0 = blockIdx.y * 64;
    const float* W; int m;
    if (k0 < 1024)      { W = Wx;    m = 0; }
    else if (k0 < 2048) { W = Wh;    m = 1; }
    else                { W = Wattn; m = 2; }
    const int kk0 = k0 - m * 1024;
    ushort* dstm = WT + (size_t)m * FH * 1024;
    int t = threadIdx.x;
    int cc = t & 63, r4 = t >> 6;
#pragma unroll
    for (int i = 0; i < 16; ++i) {
        int r = i * 4 + r4;
        Ls[r][cc] = f2b(W[(size_t)(kk0 + r) * FH + n0 + cc]);
    }
    __syncthreads();
#pragma unroll
    for (int i = 0; i < 16; ++i) {
        int nn = i * 4 + r4;
        dstm[(size_t)(n0 + nn) * 1024 + kk0 + cc] = Ls[cc][nn];
    }
}

// ---------------------------------------------------------------------------
// init: h0=c0=meanpool(A); Ab16 = bf16(A); qk0 bucket0 = sum_h h0*A,
// buckets 1..15 zero; qk1 all zero.
__global__ __launch_bounds__(256) void init_kernel(
    const float* __restrict__ Aflat, float* __restrict__ cbuf,
    ushort* __restrict__ h0buf, ushort* __restrict__ Ab16,
    float* __restrict__ qk0, float* __restrict__ qk1)
{
    __shared__ float red[4][16];
    const int n = blockIdx.x, tid = threadIdx.x;
    const int wv = tid >> 6, l = tid & 63;
    float p[16];
#pragma unroll
    for (int k = 0; k < 16; ++k) p[k] = 0.f;
#pragma unroll
    for (int u = 0; u < 4; ++u) {
        const int h = tid + u * 256;
        const size_t idx = (size_t)n * 1024 + h;
        const float4* a4 = (const float4*)(Aflat + idx * 16);
        float ar[16];
#pragma unroll
        for (int q = 0; q < 4; ++q) {
            float4 v = a4[q];
            ar[q*4+0]=v.x; ar[q*4+1]=v.y; ar[q*4+2]=v.z; ar[q*4+3]=v.w;
        }
        union { ushort us[16]; uint4 v[2]; } ob;
#pragma unroll
        for (int k = 0; k < 16; ++k) ob.us[k] = f2b(ar[k]);
        uint4* dst = (uint4*)(Ab16 + idx * 16);
        dst[0] = ob.v[0]; dst[1] = ob.v[1];

        float s = 0.f;
#pragma unroll
        for (int k = 0; k < 16; ++k) s += ar[k];
        float hv = s * 0.0625f;
        cbuf[idx] = hv;
        h0buf[idx] = f2b(hv);
#pragma unroll
        for (int k = 0; k < 16; ++k) p[k] += hv * ar[k];
    }
#pragma unroll
    for (int k = 0; k < 16; ++k) {
        float v = p[k];
        v += __shfl_xor(v, 32); v += __shfl_xor(v, 16); v += __shfl_xor(v, 8);
        v += __shfl_xor(v, 4);  v += __shfl_xor(v, 2);  v += __shfl_xor(v, 1);
        p[k] = v;
    }
    if (l == 0) {
#pragma unroll
        for (int k = 0; k < 16; ++k) red[wv][k] = p[k];
    }
    __syncthreads();
    if (tid < 16) {
        float val = red[0][tid] + red[1][tid] + red[2][tid] + red[3][tid];
#pragma unroll
        for (int bkt = 0; bkt < QB; ++bkt) {
            qk0[bkt * 2048 + n * 16 + tid] = (bkt == 0) ? val : 0.f;
            qk1[bkt * 2048 + n * 16 + tid] = 0.f;
        }
    }
}

// ---------------------------------------------------------------------------
// P2[n][j][k] = sum_h A[n][h][k] * Wattn[h][j]; 4-n batched per block.
__global__ __launch_bounds__(256) void p_gemm(
    const ushort* __restrict__ Ab16,    // [128][1024][16]
    const ushort* __restrict__ WatT,    // [4096][1024]
    ushort* __restrict__ P2)            // [128][4096][16] bf16
{
    __shared__ ushort ALDS[4 * 16 * 72];
    __shared__ ushort Bs[256 * 64];
    const int tid = threadIdx.x;
    const int wv = tid >> 6, l = tid & 63;
    const int lr = l & 15, g = l >> 4;
    const int jt = blockIdx.x, n0 = blockIdx.y * 4;
    const int snn = tid >> 6, shl = tid & 63;

    float4v acc[4][4];
#pragma unroll
    for (int i = 0; i < 4; ++i)
#pragma unroll
        for (int j = 0; j < 4; ++j) acc[i][j] = (float4v){0.f, 0.f, 0.f, 0.f};

#pragma unroll 1
    for (int kc = 0; kc < 16; ++kc) {
        __syncthreads();
        {
            const ushort* src = Ab16 + ((size_t)(n0 + snn) * 1024 + kc * 64 + shl) * 16;
            union { uint4 v[2]; ushort us[16]; } iv;
            iv.v[0] = *(const uint4*)src;
            iv.v[1] = *(const uint4*)(src + 8);
#pragma unroll
            for (int k = 0; k < 16; ++k)
                ALDS[(snn * 16 + k) * 72 + shl] = iv.us[k];
        }
#pragma unroll
        for (int i = 0; i < 8; ++i) {
            int s = i * 256 + tid;
            int r = s >> 3, c = (s & 7) ^ (r & 7);
            gll16(WatT + (size_t)(jt * 256 + r) * 1024 + kc * 64 + c * 8,
                  &Bs[s * 8]);
        }
        __syncthreads();
#pragma unroll
        for (int sub = 0; sub < 2; ++sub) {
            short8v af[4], bf[4];
#pragma unroll
            for (int nn = 0; nn < 4; ++nn)
                af[nn] = *(const short8v*)&ALDS[(nn * 16 + lr) * 72 + sub * 32 + g * 8];
#pragma unroll
            for (int nf = 0; nf < 4; ++nf) {
                int rb = wv * 64 + nf * 16 + lr;
                bf[nf] = *(const short8v*)&Bs[rb * 64 + (((sub * 4 + g) ^ (rb & 7)) * 8)];
            }
#pragma unroll
            for (int nn = 0; nn < 4; ++nn)
#pragma unroll
                for (int nf = 0; nf < 4; ++nf)
                    acc[nn][nf] = __builtin_amdgcn_mfma_f32_16x16x32_bf16(
                        af[nn], bf[nf], acc[nn][nf], 0, 0, 0);
        }
    }

#pragma unroll
    for (int nn = 0; nn < 4; ++nn)
#pragma unroll
        for (int nf = 0; nf < 4; ++nf) {
            const int j = jt * 256 + wv * 64 + nf * 16 + lr;
            union { ushort u[4]; uint2 v; } o;
#pragma unroll
            for (int jj = 0; jj < 4; ++jj) o.u[jj] = f2b(acc[nn][nf][jj]);
            *(uint2*)&P2[((size_t)(n0 + nn) * FH + j) * 16 + g * 4] = o.v;
        }
}

// ---------------------------------------------------------------------------
// Per-step kernel: 512 blocks (2/CU), 256 thr = 4 waves (2 mh x 2 kh).
// Block: 32n x 32j (8 hc x 4 gates), K = 2048 = [x_t | h], BK=128 dbuf.
// qk partials spread over QB=16 line-separated buckets (bucket = bx & 15).
__global__ __launch_bounds__(256) void step_kernel(
    const ushort* __restrict__ hcur,    // [128][1024] bf16
    ushort* __restrict__ hnext,
    const ushort* __restrict__ xb_t,    // + t*HD, row stride TT*HD
    const ushort* __restrict__ WxT,     // [4096][1024]
    const ushort* __restrict__ WhT,     // [4096][1024]
    const ushort* __restrict__ P2,      // [128][4096][16]
    const ushort* __restrict__ Ab16,    // [128][1024][16]
    const float* __restrict__ bias,
    float* __restrict__ cbuf,
    const float* __restrict__ qk_cur,   // [QB][2048]
    float* __restrict__ qk_next,
    float* __restrict__ qk_zero,
    float* __restrict__ out_t)          // + t*HD, row stride TT*HD
{
    __shared__ ushort AS[16384];
    __shared__ ushort BS[16384];
    __shared__ float accL[2 * 32 * 33];
    __shared__ float wLDS[32 * 16];

    const int tid = threadIdx.x;
    const int w = tid >> 6, l = tid & 63;
    const int mh = w & 1, kh = w >> 1;
    const int lr = l & 15, g = l >> 4;

    // XCD-chunked swizzle: each XCD owns 16 contiguous bx groups.
    const int bid = blockIdx.x;
    const int xcd = bid & 7, ii = bid >> 3;
    const int bx = xcd * 16 + (ii & 15);
    const int my = ii >> 4;
    const int n0 = my * 32;

    if (bid < 128) qk_zero[bid * 256 + tid] = 0.f;

    if (tid < 32) {   // softmax(qk/32): sum QB buckets, then exp-normalize
        const float* q = qk_cur + (n0 + tid) * 16;
        float4 s4[4];
#pragma unroll
        for (int q4 = 0; q4 < 4; ++q4) s4[q4] = ((const float4*)q)[q4];
#pragma unroll
        for (int bkt = 1; bkt < QB; ++bkt) {
            const float4* qb = (const float4*)(q + bkt * 2048);
#pragma unroll
            for (int q4 = 0; q4 < 4; ++q4) {
                float4 v = qb[q4];
                s4[q4].x += v.x; s4[q4].y += v.y; s4[q4].z += v.z; s4[q4].w += v.w;
            }
        }
        float s[16];
#pragma unroll
        for (int q4 = 0; q4 < 4; ++q4) {
            s[q4*4+0] = s4[q4].x; s[q4*4+1] = s4[q4].y;
            s[q4*4+2] = s4[q4].z; s[q4*4+3] = s4[q4].w;
        }
        float m = -1e30f;
#pragma unroll
        for (int k = 0; k < 16; ++k) { s[k] *= 0.03125f; m = fmaxf(m, s[k]); }
        float sum = 0.f;
#pragma unroll
        for (int k = 0; k < 16; ++k) { s[k] = __expf(s[k] - m); sum += s[k]; }
        float inv = 1.f / sum;
#pragma unroll
        for (int k = 0; k < 16; ++k) wLDS[tid * 16 + k] = s[k] * inv;
    }

#define STAGE(b, kc)                                                           \
    do {                                                                       \
        _Pragma("unroll")                                                      \
        for (int i = 0; i < 4; ++i) {                                          \
            int u = i * 256 + tid;                                             \
            int skh = u >> 9, rem = u & 511;                                   \
            int r = rem >> 4, c = rem & 15;                                    \
            int lc = swz(c, r);                                                \
            const ushort* src = skh                                            \
                ? hcur + (size_t)(n0 + r) * 1024 + (kc) * 128 + lc * 8         \
                : xb_t + (size_t)(n0 + r) * (TT * HD) + (kc) * 128 + lc * 8;   \
            gll16(src, AS + (((b) * 2 + skh) * 512 + rem) * 8);                \
        }                                                                      \
        _Pragma("unroll")                                                      \
        for (int i = 0; i < 4; ++i) {                                          \
            int u = i * 256 + tid;                                             \
            int skh = u >> 9, rem = u & 511;                                   \
            int r = rem >> 4, c = rem & 15;                                    \
            int lc = swz(c, r);                                                \
            int jg = (r >> 3) * 1024 + bx * 8 + (r & 7);                       \
            const ushort* src = (skh ? WhT : WxT) + (size_t)jg * 1024          \
                                + (kc) * 128 + lc * 8;                         \
            gll16(src, BS + (((b) * 2 + skh) * 512 + rem) * 8);                \
        }                                                                      \
    } while (0)

    float4v acc[2];
    acc[0] = (float4v){0.f, 0.f, 0.f, 0.f};
    acc[1] = (float4v){0.f, 0.f, 0.f, 0.f};

    STAGE(0, 0);
    __syncthreads();
    int buf = 0;
#pragma unroll 1
    for (int kc = 0; kc < 8; ++kc) {
        if (kc < 7) STAGE(buf ^ 1, kc + 1);
        const int base = (buf * 2 + kh) * 512;
        const int ra = mh * 16 + lr;
#pragma unroll
        for (int ks = 0; ks < 4; ++ks) {
            const int c = ks * 4 + g;
            short8v af = *(const short8v*)&AS[(base + ra * 16 + swz(c, ra)) * 8];
#pragma unroll
            for (int nf = 0; nf < 2; ++nf) {
                const int rb = nf * 16 + lr;
                short8v bf = *(const short8v*)&BS[(base + rb * 16 + swz(c, rb)) * 8];
                acc[nf] = __builtin_amdgcn_mfma_f32_16x16x32_bf16(af, bf, acc[nf], 0, 0, 0);
            }
        }
        __syncthreads();
        buf ^= 1;
    }
#undef STAGE

    // combine K-halves via LDS
#pragma unroll
    for (int nf = 0; nf < 2; ++nf)
#pragma unroll
        for (int jj = 0; jj < 4; ++jj)
            accL[(kh * 32 + mh * 16 + g * 4 + jj) * 33 + nf * 16 + lr] = acc[nf][jj];
    __syncthreads();

    // ---- epilogue: thread = one (n, hc) cell ----
    const int n_l = tid >> 3, hcl = tid & 7;
    const int n = n0 + n_l;
    const int hc = bx * 8 + hcl;

    float wv_[16];
#pragma unroll
    for (int k = 0; k < 16; ++k) wv_[k] = wLDS[n_l * 16 + k];

    float val[4];
#pragma unroll
    for (int q = 0; q < 4; ++q) {
        const int cq = q * 8 + hcl;
        float v = accL[n_l * 33 + cq] + accL[(32 + n_l) * 33 + cq]
                + bias[q * 1024 + hc];
        const ushort* pp = P2 + ((size_t)n * FH + q * 1024 + hc) * 16;
        union { uint4 v[2]; ushort us[16]; } pv;
        pv.v[0] = *(const uint4*)pp;
        pv.v[1] = *(const uint4*)(pp + 8);
#pragma unroll
        for (int k = 0; k < 16; ++k) v += wv_[k] * b2f(pv.us[k]);
        val[q] = v;
    }

    const size_t chidx = (size_t)n * 1024 + hc;
    float cn = sigm(val[1]) * cbuf[chidx] + sigm(val[0]) * tanhf(val[3]);
    float hv = sigm(val[2]) * tanhf(cn);
    cbuf[chidx] = cn;
    out_t[(size_t)n * (TT * HD) + hc] = hv;
    hnext[chidx] = f2b(hv);

    // qk partials: p[k] = hv * A[n][hc][k], reduced over 8 hcl lanes
    union { uint4 v[2]; ushort us[16]; } av;
    {
        const ushort* ap = Ab16 + chidx * 16;
        av.v[0] = *(const uint4*)ap;
        av.v[1] = *(const uint4*)(ap + 8);
    }
    float vv[16];
#pragma unroll
    for (int k = 0; k < 16; ++k) vv[k] = hv * b2f(av.us[k]);
    {
        bool hi = (hcl & 1);
#pragma unroll
        for (int q = 0; q < 8; ++q) {
            float send = hi ? vv[q] : vv[q + 8];
            float recv = __shfl_xor(send, 1);
            vv[q] = (hi ? vv[q + 8] : vv[q]) + recv;
        }
        hi = (hcl & 2);
#pragma unroll
        for (int q = 0; q < 4; ++q) {
            float send = hi ? vv[q] : vv[q + 4];
            float recv = __shfl_xor(send, 2);
            vv[q] = (hi ? vv[q + 4] : vv[q]) + recv;
        }
        hi = (hcl & 4);
#pragma unroll
        for (int q = 0; q < 2; ++q) {
            float send = hi ? vv[q] : vv[q + 2];
            float recv = __shfl_xor(send, 4);
            vv[q] = (hi ? vv[q + 2] : vv[q]) + recv;
        }
    }
    const int kbase = ((hcl & 1) << 3) | ((hcl & 2) << 1) | ((hcl & 4) >> 1);
    float* qdst = qk_next + (bx & (QB - 1)) * 2048 + n * 16;
    atomicAdd(qdst + kbase,     vv[0]);
    atomicAdd(qdst + kbase + 1, vv[1]);
}

// ---------------------------------------------------------------------------
extern "C" void kernel_launch(void* const* d_in, const int* in_sizes, int n_in,
                              void* d_out, int out_size, void* d_ws, size_t ws_size,
                              hipStream_t stream) {
    const float* x     = (const float*)d_in[0];
    const float* A     = (const float*)d_in[1];
    const float* Wx    = (const float*)d_in[2];
    const float* Wh    = (const float*)d_in[3];
    const float* Wattn = (const float*)d_in[4];
    const float* b     = (const float*)d_in[5];
    float* out = (float*)d_out;

    ushort* WT   = (ushort*)d_ws;                          // 3 x 8.39 MB
    ushort* WxT  = WT;
    ushort* WhT  = WT + (size_t)FH * 1024;
    ushort* WatT = WT + (size_t)2 * FH * 1024;
    ushort* xb   = WT + (size_t)3 * FH * 1024;             // 33.55 MB
    ushort* Ab16 = xb + (size_t)NB * TT * HD;              // 4.19 MB
    ushort* hb   = Ab16 + (size_t)NB * HD * 16;            // 2 x 0.26 MB
    float*  cb   = (float*)(hb + (size_t)2 * NB * HD);     // 0.52 MB
    float*  qk   = cb + (size_t)NB * HD;                   // 3 x 128 KB
    ushort* P2   = (ushort*)(qk + 3 * QSLOT);              // 16.78 MB

    cvt_x<<<8192, 256, 0, stream>>>(x, xb);
    build_wt<<<dim3(48, 64), 256, 0, stream>>>(Wx, Wh, Wattn, WT);
    init_kernel<<<NB, 256, 0, stream>>>(A, cb, hb, Ab16, qk, qk + QSLOT);
    p_gemm<<<dim3(16, 32), 256, 0, stream>>>(Ab16, WatT, P2);

    for (int t = 0; t < TT; ++t) {
        const ushort* hc = hb + (size_t)(t & 1) * NB * HD;
        ushort* hn       = hb + (size_t)((t + 1) & 1) * NB * HD;
        const float* qc  = qk + (size_t)(t % 3) * QSLOT;
        float* qn        = qk + (size_t)((t + 1) % 3) * QSLOT;
        float* qz        = qk + (size_t)((t + 2) % 3) * QSLOT;
        step_kernel<<<512, 256, 0, stream>>>(
            hc, hn, xb + (size_t)t * HD, WxT, WhT, P2, Ab16, b, cb,
            qc, qn, qz, out + (size_t)t * HD);
    }
}

// Round 10
// 1737.236 us; speedup vs baseline: 15.2476x; 1.1778x over previous
//
#include <hip/hip_runtime.h>
#include <math.h>

#define NB 128
#define TT 128
#define HD 1024
#define FH 4096
#define QB 16            // qk contention-spread buckets
#define QSLOT (QB * 2048)

typedef __attribute__((ext_vector_type(8))) short short8v;
typedef __attribute__((ext_vector_type(4))) float float4v;

__device__ __forceinline__ ushort f2b(float f) {
    union { float f; unsigned u; } v; v.f = f;
    unsigned r = (v.u + 0x7fffu + ((v.u >> 16) & 1u)) >> 16;
    return (ushort)r;
}
__device__ __forceinline__ float b2f(ushort u) {
    union { unsigned u; float f; } v; v.u = ((unsigned)u) << 16;
    return v.f;
}
__device__ __forceinline__ float sigm(float x) { return 1.f / (1.f + __expf(-x)); }
__device__ __forceinline__ void gll16(const void* g, void* l) {
    __builtin_amdgcn_global_load_lds(
        (const __attribute__((address_space(1))) void*)g,
        (__attribute__((address_space(3))) void*)l,
        16, 0, 0);
}
// XOR chunk swizzle within a 16-chunk (256B) row; involution in low 3 bits.
__device__ __forceinline__ int swz(int c, int r) {
    return (c & 8) | ((c & 7) ^ (r & 7));
}

// ---------------------------------------------------------------------------
// x fp32 -> bf16 ([N][T][D] preserved) — FULLK fallback only
__global__ __launch_bounds__(256) void cvt_x(const float* __restrict__ x,
                                             ushort* __restrict__ xb) {
    size_t i = (size_t)blockIdx.x * 256 + threadIdx.x;
    const float4* p = (const float4*)x + i * 2;
    float4 va = p[0], vb = p[1];
    union { ushort u[8]; uint4 v; } o;
    o.u[0] = f2b(va.x); o.u[1] = f2b(va.y); o.u[2] = f2b(va.z); o.u[3] = f2b(va.w);
    o.u[4] = f2b(vb.x); o.u[5] = f2b(vb.y); o.u[6] = f2b(vb.z); o.u[7] = f2b(vb.w);
    ((uint4*)xb)[i] = o.v;
}

// ---------------------------------------------------------------------------
// WT layout: [WxT (4096x1024)] [WhT (4096x1024)] [WatT (4096x1024)], bf16.
__global__ __launch_bounds__(256) void build_wt(const float* __restrict__ Wx,
                                                const float* __restrict__ Wh,
                                                const float* __restrict__ Wattn,
                                                ushort* __restrict__ WT) {
    __shared__ ushort Ls[64][65];
    int k0 = blockIdx.x * 64, n0 = blockIdx.y * 64;
    const float* W; int m;
    if (k0 < 1024)      { W = Wx;    m = 0; }
    else if (k0 < 2048) { W = Wh;    m = 1; }
    else                { W = Wattn; m = 2; }
    const int kk0 = k0 - m * 1024;
    ushort* dstm = WT + (size_t)m * FH * 1024;
    int t = threadIdx.x;
    int cc = t & 63, r4 = t >> 6;
#pragma unroll
    for (int i = 0; i < 16; ++i) {
        int r = i * 4 + r4;
        Ls[r][cc] = f2b(W[(size_t)(kk0 + r) * FH + n0 + cc]);
    }
    __syncthreads();
#pragma unroll
    for (int i = 0; i < 16; ++i) {
        int nn = i * 4 + r4;
        dstm[(size_t)(n0 + nn) * 1024 + kk0 + cc] = Ls[cc][nn];
    }
}

// ---------------------------------------------------------------------------
// init: h0=c0=meanpool(A); Ab16 = bf16(A); qk0 bucket0 = sum_h h0*A,
// buckets 1..15 zero; qk1 all zero.
__global__ __launch_bounds__(256) void init_kernel(
    const float* __restrict__ Aflat, float* __restrict__ cbuf,
    ushort* __restrict__ h0buf, ushort* __restrict__ Ab16,
    float* __restrict__ qk0, float* __restrict__ qk1)
{
    __shared__ float red[4][16];
    const int n = blockIdx.x, tid = threadIdx.x;
    const int wv = tid >> 6, l = tid & 63;
    float p[16];
#pragma unroll
    for (int k = 0; k < 16; ++k) p[k] = 0.f;
#pragma unroll
    for (int u = 0; u < 4; ++u) {
        const int h = tid + u * 256;
        const size_t idx = (size_t)n * 1024 + h;
        const float4* a4 = (const float4*)(Aflat + idx * 16);
        float ar[16];
#pragma unroll
        for (int q = 0; q < 4; ++q) {
            float4 v = a4[q];
            ar[q*4+0]=v.x; ar[q*4+1]=v.y; ar[q*4+2]=v.z; ar[q*4+3]=v.w;
        }
        union { ushort us[16]; uint4 v[2]; } ob;
#pragma unroll
        for (int k = 0; k < 16; ++k) ob.us[k] = f2b(ar[k]);
        uint4* dst = (uint4*)(Ab16 + idx * 16);
        dst[0] = ob.v[0]; dst[1] = ob.v[1];

        float s = 0.f;
#pragma unroll
        for (int k = 0; k < 16; ++k) s += ar[k];
        float hv = s * 0.0625f;
        cbuf[idx] = hv;
        h0buf[idx] = f2b(hv);
#pragma unroll
        for (int k = 0; k < 16; ++k) p[k] += hv * ar[k];
    }
#pragma unroll
    for (int k = 0; k < 16; ++k) {
        float v = p[k];
        v += __shfl_xor(v, 32); v += __shfl_xor(v, 16); v += __shfl_xor(v, 8);
        v += __shfl_xor(v, 4);  v += __shfl_xor(v, 2);  v += __shfl_xor(v, 1);
        p[k] = v;
    }
    if (l == 0) {
#pragma unroll
        for (int k = 0; k < 16; ++k) red[wv][k] = p[k];
    }
    __syncthreads();
    if (tid < 16) {
        float val = red[0][tid] + red[1][tid] + red[2][tid] + red[3][tid];
#pragma unroll
        for (int bkt = 0; bkt < QB; ++bkt) {
            qk0[bkt * 2048 + n * 16 + tid] = (bkt == 0) ? val : 0.f;
            qk1[bkt * 2048 + n * 16 + tid] = 0.f;
        }
    }
}

// ---------------------------------------------------------------------------
// P2[n][j][k] = sum_h A[n][h][k] * Wattn[h][j]; 4-n batched per block.
__global__ __launch_bounds__(256) void p_gemm(
    const ushort* __restrict__ Ab16,    // [128][1024][16]
    const ushort* __restrict__ WatT,    // [4096][1024]
    ushort* __restrict__ P2)            // [128][4096][16] bf16
{
    __shared__ ushort ALDS[4 * 16 * 72];
    __shared__ ushort Bs[256 * 64];
    const int tid = threadIdx.x;
    const int wv = tid >> 6, l = tid & 63;
    const int lr = l & 15, g = l >> 4;
    const int jt = blockIdx.x, n0 = blockIdx.y * 4;
    const int snn = tid >> 6, shl = tid & 63;

    float4v acc[4][4];
#pragma unroll
    for (int i = 0; i < 4; ++i)
#pragma unroll
        for (int j = 0; j < 4; ++j) acc[i][j] = (float4v){0.f, 0.f, 0.f, 0.f};

#pragma unroll 1
    for (int kc = 0; kc < 16; ++kc) {
        __syncthreads();
        {
            const ushort* src = Ab16 + ((size_t)(n0 + snn) * 1024 + kc * 64 + shl) * 16;
            union { uint4 v[2]; ushort us[16]; } iv;
            iv.v[0] = *(const uint4*)src;
            iv.v[1] = *(const uint4*)(src + 8);
#pragma unroll
            for (int k = 0; k < 16; ++k)
                ALDS[(snn * 16 + k) * 72 + shl] = iv.us[k];
        }
#pragma unroll
        for (int i = 0; i < 8; ++i) {
            int s = i * 256 + tid;
            int r = s >> 3, c = (s & 7) ^ (r & 7);
            gll16(WatT + (size_t)(jt * 256 + r) * 1024 + kc * 64 + c * 8,
                  &Bs[s * 8]);
        }
        __syncthreads();
#pragma unroll
        for (int sub = 0; sub < 2; ++sub) {
            short8v af[4], bf[4];
#pragma unroll
            for (int nn = 0; nn < 4; ++nn)
                af[nn] = *(const short8v*)&ALDS[(nn * 16 + lr) * 72 + sub * 32 + g * 8];
#pragma unroll
            for (int nf = 0; nf < 4; ++nf) {
                int rb = wv * 64 + nf * 16 + lr;
                bf[nf] = *(const short8v*)&Bs[rb * 64 + (((sub * 4 + g) ^ (rb & 7)) * 8)];
            }
#pragma unroll
            for (int nn = 0; nn < 4; ++nn)
#pragma unroll
                for (int nf = 0; nf < 4; ++nf)
                    acc[nn][nf] = __builtin_amdgcn_mfma_f32_16x16x32_bf16(
                        af[nn], bf[nf], acc[nn][nf], 0, 0, 0);
        }
    }

#pragma unroll
    for (int nn = 0; nn < 4; ++nn)
#pragma unroll
        for (int nf = 0; nf < 4; ++nf) {
            const int j = jt * 256 + wv * 64 + nf * 16 + lr;
            union { ushort u[4]; uint2 v; } o;
#pragma unroll
            for (int jj = 0; jj < 4; ++jj) o.u[jj] = f2b(acc[nn][nf][jj]);
            *(uint2*)&P2[((size_t)(n0 + nn) * FH + j) * 16 + g * 4] = o.v;
        }
}

// ---------------------------------------------------------------------------
// XA[t][n][j] = x[n,t,:] @ Wx (bf16 out). 16384 x 1024 x 4096.
// v2: BK=64 dbuf (64 KB LDS -> 2 blocks/CU), A reg-staged from fp32 x,
// B via gll16. grid (32 ntile, 128 n); 256 thr = 4 waves (2wm x 2wn, 64x64).
__global__ __launch_bounds__(256) void xa_gemm2(
    const float* __restrict__ x,        // [128][128][1024] fp32
    const ushort* __restrict__ WxT,     // [4096][1024]
    ushort* __restrict__ xab)           // [128t][128n][4096]
{
    __shared__ ushort As[2][128 * 64];  // 16 KB each
    __shared__ ushort Bs[2][128 * 64];
    const int tid = threadIdx.x;
    const int w = tid >> 6, l = tid & 63;
    const int wm = w >> 1, wn = w & 1;
    const int lr = l & 15, g = l >> 4;
    const int n0 = blockIdx.x * 128;
    const int mt = blockIdx.y;          // = n; local row r = t
    const float* Ax = x + (size_t)mt * 128 * 1024;
    const ushort* Bb = WxT + (size_t)n0 * 1024;

#define STAGEA(b, kf)                                                          \
    do {                                                                       \
        _Pragma("unroll")                                                      \
        for (int i = 0; i < 4; ++i) {                                          \
            int u = i * 256 + tid;                                             \
            int r = u >> 3, c = u & 7;                                         \
            const float* s = Ax + (size_t)r * 1024 + (kf) + c * 8;             \
            float4 v0 = *(const float4*)s;                                     \
            float4 v1 = *(const float4*)(s + 4);                               \
            union { ushort us[8]; uint4 v; } o;                                \
            o.us[0]=f2b(v0.x); o.us[1]=f2b(v0.y); o.us[2]=f2b(v0.z);           \
            o.us[3]=f2b(v0.w); o.us[4]=f2b(v1.x); o.us[5]=f2b(v1.y);           \
            o.us[6]=f2b(v1.z); o.us[7]=f2b(v1.w);                              \
            *(uint4*)&As[b][(r * 8 + (c ^ (r & 7))) * 8] = o.v;                \
        }                                                                      \
    } while (0)
#define STAGEB(b, kf)                                                          \
    do {                                                                       \
        _Pragma("unroll")                                                      \
        for (int i = 0; i < 4; ++i) {                                          \
            int s = i * 256 + tid;                                             \
            int r = s >> 3, c = s & 7;                                         \
            gll16(Bb + (size_t)r * 1024 + (kf) + (c ^ (r & 7)) * 8,            \
                  &Bs[b][s * 8]);                                              \
        }                                                                      \
    } while (0)

    float4v acc[4][4];
#pragma unroll
    for (int i = 0; i < 4; ++i)
#pragma unroll
        for (int j = 0; j < 4; ++j) acc[i][j] = (float4v){0.f, 0.f, 0.f, 0.f};

    STAGEA(0, 0);
    STAGEB(0, 0);
    __syncthreads();
    int buf = 0;
#pragma unroll 1
    for (int kc = 0; kc < 16; ++kc) {
        if (kc < 15) { STAGEA(buf ^ 1, (kc + 1) * 64); STAGEB(buf ^ 1, (kc + 1) * 64); }
        const ushort* Ab = As[buf];
        const ushort* Bbuf = Bs[buf];
#pragma unroll
        for (int sub = 0; sub < 2; ++sub) {
            short8v af[4], bf[4];
#pragma unroll
            for (int mf = 0; mf < 4; ++mf) {
                int ra = wm * 64 + mf * 16 + lr;
                af[mf] = *(const short8v*)&Ab[ra * 64 + (((sub * 4 + g) ^ (ra & 7)) * 8)];
            }
#pragma unroll
            for (int nf = 0; nf < 4; ++nf) {
                int rb = wn * 64 + nf * 16 + lr;
                bf[nf] = *(const short8v*)&Bbuf[rb * 64 + (((sub * 4 + g) ^ (rb & 7)) * 8)];
            }
#pragma unroll
            for (int mf = 0; mf < 4; ++mf)
#pragma unroll
                for (int nf = 0; nf < 4; ++nf)
                    acc[mf][nf] = __builtin_amdgcn_mfma_f32_16x16x32_bf16(
                        af[mf], bf[nf], acc[mf][nf], 0, 0, 0);
        }
        __syncthreads();
        buf ^= 1;
    }
#undef STAGEA
#undef STAGEB

#pragma unroll
    for (int mf = 0; mf < 4; ++mf)
#pragma unroll
        for (int nf = 0; nf < 4; ++nf) {
            const int col = n0 + wn * 64 + nf * 16 + lr;
#pragma unroll
            for (int j = 0; j < 4; ++j) {
                const int rl = wm * 64 + mf * 16 + g * 4 + j;   // = t
                xab[((size_t)rl * NB + mt) * FH + col] = f2b(acc[mf][nf][j]);
            }
        }
}

// ---------------------------------------------------------------------------
// Per-step kernel. XAF=1: K=1024 (h @ WhT), XA added in epilogue, 4 K-iters.
// XAF=0: K=2048 ([x_t|h]), 8 K-iters (round-9 proven fallback).
// 512 blocks (2/CU), 256 thr = 4 waves (2 mh x 2 kh); 32n x 32j per block.
template <int XAF>
__global__ __launch_bounds__(256) void step_kernel(
    const ushort* __restrict__ hcur,    // [128][1024] bf16
    ushort* __restrict__ hnext,
    const ushort* __restrict__ xb_t,    // XAF=0: + t*HD, row stride TT*HD
    const ushort* __restrict__ xab_t,   // XAF=1: + t*NB*FH
    const ushort* __restrict__ WxT,     // [4096][1024]
    const ushort* __restrict__ WhT,     // [4096][1024]
    const ushort* __restrict__ P2,      // [128][4096][16]
    const ushort* __restrict__ Ab16,    // [128][1024][16]
    const float* __restrict__ bias,
    float* __restrict__ cbuf,
    const float* __restrict__ qk_cur,   // [QB][2048]
    float* __restrict__ qk_next,
    float* __restrict__ qk_zero,
    float* __restrict__ out_t)          // + t*HD, row stride TT*HD
{
    __shared__ ushort AS[16384];
    __shared__ ushort BS[16384];
    __shared__ float accL[2 * 32 * 33];
    __shared__ float wLDS[32 * 16];

    const int tid = threadIdx.x;
    const int w = tid >> 6, l = tid & 63;
    const int mh = w & 1, kh = w >> 1;
    const int lr = l & 15, g = l >> 4;

    // XCD-chunked swizzle
    const int bid = blockIdx.x;
    const int xcd = bid & 7, ii = bid >> 3;
    const int bx = xcd * 16 + (ii & 15);
    const int my = ii >> 4;
    const int n0 = my * 32;

    if (bid < 128) qk_zero[bid * 256 + tid] = 0.f;

    if (tid < 32) {   // softmax(qk/32): sum QB buckets, then exp-normalize
        const float* q = qk_cur + (n0 + tid) * 16;
        float4 s4[4];
#pragma unroll
        for (int q4 = 0; q4 < 4; ++q4) s4[q4] = ((const float4*)q)[q4];
#pragma unroll
        for (int bkt = 1; bkt < QB; ++bkt) {
            const float4* qb = (const float4*)(q + bkt * 2048);
#pragma unroll
            for (int q4 = 0; q4 < 4; ++q4) {
                float4 v = qb[q4];
                s4[q4].x += v.x; s4[q4].y += v.y; s4[q4].z += v.z; s4[q4].w += v.w;
            }
        }
        float s[16];
#pragma unroll
        for (int q4 = 0; q4 < 4; ++q4) {
            s[q4*4+0] = s4[q4].x; s[q4*4+1] = s4[q4].y;
            s[q4*4+2] = s4[q4].z; s[q4*4+3] = s4[q4].w;
        }
        float m = -1e30f;
#pragma unroll
        for (int k = 0; k < 16; ++k) { s[k] *= 0.03125f; m = fmaxf(m, s[k]); }
        float sum = 0.f;
#pragma unroll
        for (int k = 0; k < 16; ++k) { s[k] = __expf(s[k] - m); sum += s[k]; }
        float inv = 1.f / sum;
#pragma unroll
        for (int k = 0; k < 16; ++k) wLDS[tid * 16 + k] = s[k] * inv;
    }

    // XAF=1: kh-half covers K [kh*512, kh*512+512) of hcur/WhT, 4 iters of 128.
    // XAF=0: kh=0 -> x_t/WxT K=1024, kh=1 -> hcur/WhT K=1024, 8 iters of 128.
#define STAGE(b, kc)                                                           \
    do {                                                                       \
        _Pragma("unroll")                                                      \
        for (int i = 0; i < 4; ++i) {                                          \
            int u = i * 256 + tid;                                             \
            int skh = u >> 9, rem = u & 511;                                   \
            int r = rem >> 4, c = rem & 15;                                    \
            int lc = swz(c, r);                                                \
            const ushort* src;                                                 \
            if (XAF == 1)                                                      \
                src = hcur + (size_t)(n0 + r) * 1024 + skh * 512               \
                      + (kc) * 128 + lc * 8;                                   \
            else                                                               \
                src = skh                                                      \
                    ? hcur + (size_t)(n0 + r) * 1024 + (kc) * 128 + lc * 8     \
                    : xb_t + (size_t)(n0 + r) * (TT * HD) + (kc) * 128 + lc * 8;\
            gll16(src, AS + (((b) * 2 + skh) * 512 + rem) * 8);                \
        }                                                                      \
        _Pragma("unroll")                                                      \
        for (int i = 0; i < 4; ++i) {                                          \
            int u = i * 256 + tid;                                             \
            int skh = u >> 9, rem = u & 511;                                   \
            int r = rem >> 4, c = rem & 15;                                    \
            int lc = swz(c, r);                                                \
            int jg = (r >> 3) * 1024 + bx * 8 + (r & 7);                       \
            const ushort* src;                                                 \
            if (XAF == 1)                                                      \
                src = WhT + (size_t)jg * 1024 + skh * 512 + (kc) * 128 + lc * 8;\
            else                                                               \
                src = (skh ? WhT : WxT) + (size_t)jg * 1024                    \
                      + (kc) * 128 + lc * 8;                                   \
            gll16(src, BS + (((b) * 2 + skh) * 512 + rem) * 8);                \
        }                                                                      \
    } while (0)

    float4v acc[2];
    acc[0] = (float4v){0.f, 0.f, 0.f, 0.f};
    acc[1] = (float4v){0.f, 0.f, 0.f, 0.f};

    const int NK = (XAF == 1) ? 4 : 8;
    STAGE(0, 0);
    __syncthreads();
    int buf = 0;
#pragma unroll 1
    for (int kc = 0; kc < NK; ++kc) {
        if (kc + 1 < NK) STAGE(buf ^ 1, kc + 1);
        const int base = (buf * 2 + kh) * 512;
        const int ra = mh * 16 + lr;
#pragma unroll
        for (int ks = 0; ks < 4; ++ks) {
            const int c = ks * 4 + g;
            short8v af = *(const short8v*)&AS[(base + ra * 16 + swz(c, ra)) * 8];
#pragma unroll
            for (int nf = 0; nf < 2; ++nf) {
                const int rb = nf * 16 + lr;
                short8v bf = *(const short8v*)&BS[(base + rb * 16 + swz(c, rb)) * 8];
                acc[nf] = __builtin_amdgcn_mfma_f32_16x16x32_bf16(af, bf, acc[nf], 0, 0, 0);
            }
        }
        __syncthreads();
        buf ^= 1;
    }
#undef STAGE

    // combine K-halves via LDS
#pragma unroll
    for (int nf = 0; nf < 2; ++nf)
#pragma unroll
        for (int jj = 0; jj < 4; ++jj)
            accL[(kh * 32 + mh * 16 + g * 4 + jj) * 33 + nf * 16 + lr] = acc[nf][jj];
    __syncthreads();

    // ---- epilogue: thread = one (n, hc) cell ----
    const int n_l = tid >> 3, hcl = tid & 7;
    const int n = n0 + n_l;
    const int hc = bx * 8 + hcl;

    float wv_[16];
#pragma unroll
    for (int k = 0; k < 16; ++k) wv_[k] = wLDS[n_l * 16 + k];

    float val[4];
#pragma unroll
    for (int q = 0; q < 4; ++q) {
        const int cq = q * 8 + hcl;
        float v = accL[n_l * 33 + cq] + accL[(32 + n_l) * 33 + cq]
                + bias[q * 1024 + hc];
        if (XAF == 1) v += b2f(xab_t[(size_t)n * FH + q * 1024 + hc]);
        const ushort* pp = P2 + ((size_t)n * FH + q * 1024 + hc) * 16;
        union { uint4 v[2]; ushort us[16]; } pv;
        pv.v[0] = *(const uint4*)pp;
        pv.v[1] = *(const uint4*)(pp + 8);
#pragma unroll
        for (int k = 0; k < 16; ++k) v += wv_[k] * b2f(pv.us[k]);
        val[q] = v;
    }

    const size_t chidx = (size_t)n * 1024 + hc;
    float cn = sigm(val[1]) * cbuf[chidx] + sigm(val[0]) * tanhf(val[3]);
    float hv = sigm(val[2]) * tanhf(cn);
    cbuf[chidx] = cn;
    out_t[(size_t)n * (TT * HD) + hc] = hv;
    hnext[chidx] = f2b(hv);

    // qk partials: p[k] = hv * A[n][hc][k], reduced over 8 hcl lanes
    union { uint4 v[2]; ushort us[16]; } av;
    {
        const ushort* ap = Ab16 + chidx * 16;
        av.v[0] = *(const uint4*)ap;
        av.v[1] = *(const uint4*)(ap + 8);
    }
    float vv[16];
#pragma unroll
    for (int k = 0; k < 16; ++k) vv[k] = hv * b2f(av.us[k]);
    {
        bool hi = (hcl & 1);
#pragma unroll
        for (int q = 0; q < 8; ++q) {
            float send = hi ? vv[q] : vv[q + 8];
            float recv = __shfl_xor(send, 1);
            vv[q] = (hi ? vv[q + 8] : vv[q]) + recv;
        }
        hi = (hcl & 2);
#pragma unroll
        for (int q = 0; q < 4; ++q) {
            float send = hi ? vv[q] : vv[q + 4];
            float recv = __shfl_xor(send, 2);
            vv[q] = (hi ? vv[q + 4] : vv[q]) + recv;
        }
        hi = (hcl & 4);
#pragma unroll
        for (int q = 0; q < 2; ++q) {
            float send = hi ? vv[q] : vv[q + 2];
            float recv = __shfl_xor(send, 4);
            vv[q] = (hi ? vv[q + 2] : vv[q]) + recv;
        }
    }
    const int kbase = ((hcl & 1) << 3) | ((hcl & 2) << 1) | ((hcl & 4) >> 1);
    float* qdst = qk_next + (bx & (QB - 1)) * 2048 + n * 16;
    atomicAdd(qdst + kbase,     vv[0]);
    atomicAdd(qdst + kbase + 1, vv[1]);
}

// ---------------------------------------------------------------------------
extern "C" void kernel_launch(void* const* d_in, const int* in_sizes, int n_in,
                              void* d_out, int out_size, void* d_ws, size_t ws_size,
                              hipStream_t stream) {
    const float* x     = (const float*)d_in[0];
    const float* A     = (const float*)d_in[1];
    const float* Wx    = (const float*)d_in[2];
    const float* Wh    = (const float*)d_in[3];
    const float* Wattn = (const float*)d_in[4];
    const float* b     = (const float*)d_in[5];
    float* out = (float*)d_out;

    ushort* WT   = (ushort*)d_ws;                          // 3 x 8.39 MB
    ushort* WxT  = WT;
    ushort* WhT  = WT + (size_t)FH * 1024;
    ushort* WatT = WT + (size_t)2 * FH * 1024;
    ushort* Ab16 = WT + (size_t)3 * FH * 1024;             // 4.19 MB
    ushort* hb   = Ab16 + (size_t)NB * HD * 16;            // 2 x 0.26 MB
    float*  cb   = (float*)(hb + (size_t)2 * NB * HD);     // 0.52 MB
    float*  qk   = cb + (size_t)NB * HD;                   // 3 x 128 KB
    ushort* P2   = (ushort*)(qk + 3 * QSLOT);              // 16.78 MB
    ushort* tail = P2 + (size_t)NB * FH * 16;              // XA (134.2MB) or xb (33.55MB)

    const size_t base  = (size_t)((char*)tail - (char*)d_ws);
    const size_t xasz  = (size_t)TT * NB * FH * 2;         // 134.2 MB
    const size_t xbsz  = (size_t)NB * TT * HD * 2;         // 33.55 MB

    build_wt<<<dim3(48, 64), 256, 0, stream>>>(Wx, Wh, Wattn, WT);
    init_kernel<<<NB, 256, 0, stream>>>(A, cb, hb, Ab16, qk, qk + QSLOT);
    p_gemm<<<dim3(16, 32), 256, 0, stream>>>(Ab16, WatT, P2);

    if (ws_size >= base + xasz) {
        ushort* xab = tail;
        xa_gemm2<<<dim3(32, 128), 256, 0, stream>>>(x, WxT, xab);
        for (int t = 0; t < TT; ++t) {
            const ushort* hc = hb + (size_t)(t & 1) * NB * HD;
            ushort* hn       = hb + (size_t)((t + 1) & 1) * NB * HD;
            const float* qc  = qk + (size_t)(t % 3) * QSLOT;
            float* qn        = qk + (size_t)((t + 1) % 3) * QSLOT;
            float* qz        = qk + (size_t)((t + 2) % 3) * QSLOT;
            step_kernel<1><<<512, 256, 0, stream>>>(
                hc, hn, nullptr, xab + (size_t)t * NB * FH, WxT, WhT, P2, Ab16,
                b, cb, qc, qn, qz, out + (size_t)t * HD);
        }
    } else {
        ushort* xb = tail;
        cvt_x<<<8192, 256, 0, stream>>>(x, xb);
        for (int t = 0; t < TT; ++t) {
            const ushort* hc = hb + (size_t)(t & 1) * NB * HD;
            ushort* hn       = hb + (size_t)((t + 1) & 1) * NB * HD;
            const float* qc  = qk + (size_t)(t % 3) * QSLOT;
            float* qn        = qk + (size_t)((t + 1) % 3) * QSLOT;
            float* qz        = qk + (size_t)((t + 2) % 3) * QSLOT;
            step_kernel<0><<<512, 256, 0, stream>>>(
                hc, hn, xb + (size_t)t * HD, nullptr, WxT, WhT, P2, Ab16,
                b, cb, qc, qn, qz, out + (size_t)t * HD);
        }
    }
}

// Round 11
// 1673.991 us; speedup vs baseline: 15.8236x; 1.0378x over previous
//
#include <hip/hip_runtime.h>
#include <math.h>

#define NB 128
#define TT 128
#define HD 1024
#define FH 4096
#define QB 16            // qk contention-spread buckets
#define QSLOT (QB * 2048)

typedef __attribute__((ext_vector_type(8))) short short8v;
typedef __attribute__((ext_vector_type(4))) float float4v;

__device__ __forceinline__ ushort f2b(float f) {
    union { float f; unsigned u; } v; v.f = f;
    unsigned r = (v.u + 0x7fffu + ((v.u >> 16) & 1u)) >> 16;
    return (ushort)r;
}
__device__ __forceinline__ float b2f(ushort u) {
    union { unsigned u; float f; } v; v.u = ((unsigned)u) << 16;
    return v.f;
}
// fast sigmoid / tanh: v_exp + v_rcp, correct saturation at +-1 / {0,1}
__device__ __forceinline__ float sigm(float x) {
    return __builtin_amdgcn_rcpf(1.f + __expf(-x));
}
__device__ __forceinline__ float tanh_fast(float x) {
    return 1.f - 2.f * __builtin_amdgcn_rcpf(1.f + __expf(2.f * x));
}
__device__ __forceinline__ void gll16(const void* g, void* l) {
    __builtin_amdgcn_global_load_lds(
        (const __attribute__((address_space(1))) void*)g,
        (__attribute__((address_space(3))) void*)l,
        16, 0, 0);
}
// XOR chunk swizzle within a 16-chunk (256B) row; involution in low 3 bits.
__device__ __forceinline__ int swz(int c, int r) {
    return (c & 8) | ((c & 7) ^ (r & 7));
}

// ---------------------------------------------------------------------------
// x fp32 -> bf16 ([N][T][D] preserved)
__global__ __launch_bounds__(256) void cvt_x(const float* __restrict__ x,
                                             ushort* __restrict__ xb) {
    size_t i = (size_t)blockIdx.x * 256 + threadIdx.x;
    const float4* p = (const float4*)x + i * 2;
    float4 va = p[0], vb = p[1];
    union { ushort u[8]; uint4 v; } o;
    o.u[0] = f2b(va.x); o.u[1] = f2b(va.y); o.u[2] = f2b(va.z); o.u[3] = f2b(va.w);
    o.u[4] = f2b(vb.x); o.u[5] = f2b(vb.y); o.u[6] = f2b(vb.z); o.u[7] = f2b(vb.w);
    ((uint4*)xb)[i] = o.v;
}

// ---------------------------------------------------------------------------
// WT layout: [WxT (4096x1024)] [WhT (4096x1024)] [WatT (4096x1024)], bf16.
__global__ __launch_bounds__(256) void build_wt(const float* __restrict__ Wx,
                                                const float* __restrict__ Wh,
                                                const float* __restrict__ Wattn,
                                                ushort* __restrict__ WT) {
    __shared__ ushort Ls[64][65];
    int k0 = blockIdx.x * 64, n0 = blockIdx.y * 64;
    const float* W; int m;
    if (k0 < 1024)      { W = Wx;    m = 0; }
    else if (k0 < 2048) { W = Wh;    m = 1; }
    else                { W = Wattn; m = 2; }
    const int kk0 = k0 - m * 1024;
    ushort* dstm = WT + (size_t)m * FH * 1024;
    int t = threadIdx.x;
    int cc = t & 63, r4 = t >> 6;
#pragma unroll
    for (int i = 0; i < 16; ++i) {
        int r = i * 4 + r4;
        Ls[r][cc] = f2b(W[(size_t)(kk0 + r) * FH + n0 + cc]);
    }
    __syncthreads();
#pragma unroll
    for (int i = 0; i < 16; ++i) {
        int nn = i * 4 + r4;
        dstm[(size_t)(n0 + nn) * 1024 + kk0 + cc] = Ls[cc][nn];
    }
}

// ---------------------------------------------------------------------------
// init: h0=c0=meanpool(A); Ab16 = bf16(A); qk0 bucket0 = sum_h h0*A,
// buckets 1..15 zero; qk1 all zero.
__global__ __launch_bounds__(256) void init_kernel(
    const float* __restrict__ Aflat, float* __restrict__ cbuf,
    ushort* __restrict__ h0buf, ushort* __restrict__ Ab16,
    float* __restrict__ qk0, float* __restrict__ qk1)
{
    __shared__ float red[4][16];
    const int n = blockIdx.x, tid = threadIdx.x;
    const int wv = tid >> 6, l = tid & 63;
    float p[16];
#pragma unroll
    for (int k = 0; k < 16; ++k) p[k] = 0.f;
#pragma unroll
    for (int u = 0; u < 4; ++u) {
        const int h = tid + u * 256;
        const size_t idx = (size_t)n * 1024 + h;
        const float4* a4 = (const float4*)(Aflat + idx * 16);
        float ar[16];
#pragma unroll
        for (int q = 0; q < 4; ++q) {
            float4 v = a4[q];
            ar[q*4+0]=v.x; ar[q*4+1]=v.y; ar[q*4+2]=v.z; ar[q*4+3]=v.w;
        }
        union { ushort us[16]; uint4 v[2]; } ob;
#pragma unroll
        for (int k = 0; k < 16; ++k) ob.us[k] = f2b(ar[k]);
        uint4* dst = (uint4*)(Ab16 + idx * 16);
        dst[0] = ob.v[0]; dst[1] = ob.v[1];

        float s = 0.f;
#pragma unroll
        for (int k = 0; k < 16; ++k) s += ar[k];
        float hv = s * 0.0625f;
        cbuf[idx] = hv;
        h0buf[idx] = f2b(hv);
#pragma unroll
        for (int k = 0; k < 16; ++k) p[k] += hv * ar[k];
    }
#pragma unroll
    for (int k = 0; k < 16; ++k) {
        float v = p[k];
        v += __shfl_xor(v, 32); v += __shfl_xor(v, 16); v += __shfl_xor(v, 8);
        v += __shfl_xor(v, 4);  v += __shfl_xor(v, 2);  v += __shfl_xor(v, 1);
        p[k] = v;
    }
    if (l == 0) {
#pragma unroll
        for (int k = 0; k < 16; ++k) red[wv][k] = p[k];
    }
    __syncthreads();
    if (tid < 16) {
        float val = red[0][tid] + red[1][tid] + red[2][tid] + red[3][tid];
#pragma unroll
        for (int bkt = 0; bkt < QB; ++bkt) {
            qk0[bkt * 2048 + n * 16 + tid] = (bkt == 0) ? val : 0.f;
            qk1[bkt * 2048 + n * 16 + tid] = 0.f;
        }
    }
}

// ---------------------------------------------------------------------------
// P2[n][j][k] = sum_h A[n][h][k] * Wattn[h][j]; 4-n batched per block.
__global__ __launch_bounds__(256) void p_gemm(
    const ushort* __restrict__ Ab16,    // [128][1024][16]
    const ushort* __restrict__ WatT,    // [4096][1024]
    ushort* __restrict__ P2)            // [128][4096][16] bf16
{
    __shared__ ushort ALDS[4 * 16 * 72];
    __shared__ ushort Bs[256 * 64];
    const int tid = threadIdx.x;
    const int wv = tid >> 6, l = tid & 63;
    const int lr = l & 15, g = l >> 4;
    const int jt = blockIdx.x, n0 = blockIdx.y * 4;
    const int snn = tid >> 6, shl = tid & 63;

    float4v acc[4][4];
#pragma unroll
    for (int i = 0; i < 4; ++i)
#pragma unroll
        for (int j = 0; j < 4; ++j) acc[i][j] = (float4v){0.f, 0.f, 0.f, 0.f};

#pragma unroll 1
    for (int kc = 0; kc < 16; ++kc) {
        __syncthreads();
        {
            const ushort* src = Ab16 + ((size_t)(n0 + snn) * 1024 + kc * 64 + shl) * 16;
            union { uint4 v[2]; ushort us[16]; } iv;
            iv.v[0] = *(const uint4*)src;
            iv.v[1] = *(const uint4*)(src + 8);
#pragma unroll
            for (int k = 0; k < 16; ++k)
                ALDS[(snn * 16 + k) * 72 + shl] = iv.us[k];
        }
#pragma unroll
        for (int i = 0; i < 8; ++i) {
            int s = i * 256 + tid;
            int r = s >> 3, c = (s & 7) ^ (r & 7);
            gll16(WatT + (size_t)(jt * 256 + r) * 1024 + kc * 64 + c * 8,
                  &Bs[s * 8]);
        }
        __syncthreads();
#pragma unroll
        for (int sub = 0; sub < 2; ++sub) {
            short8v af[4], bf[4];
#pragma unroll
            for (int nn = 0; nn < 4; ++nn)
                af[nn] = *(const short8v*)&ALDS[(nn * 16 + lr) * 72 + sub * 32 + g * 8];
#pragma unroll
            for (int nf = 0; nf < 4; ++nf) {
                int rb = wv * 64 + nf * 16 + lr;
                bf[nf] = *(const short8v*)&Bs[rb * 64 + (((sub * 4 + g) ^ (rb & 7)) * 8)];
            }
#pragma unroll
            for (int nn = 0; nn < 4; ++nn)
#pragma unroll
                for (int nf = 0; nf < 4; ++nf)
                    acc[nn][nf] = __builtin_amdgcn_mfma_f32_16x16x32_bf16(
                        af[nn], bf[nf], acc[nn][nf], 0, 0, 0);
        }
    }

#pragma unroll
    for (int nn = 0; nn < 4; ++nn)
#pragma unroll
        for (int nf = 0; nf < 4; ++nf) {
            const int j = jt * 256 + wv * 64 + nf * 16 + lr;
            union { ushort u[4]; uint2 v; } o;
#pragma unroll
            for (int jj = 0; jj < 4; ++jj) o.u[jj] = f2b(acc[nn][nf][jj]);
            *(uint2*)&P2[((size_t)(n0 + nn) * FH + j) * 16 + g * 4] = o.v;
        }
}

// ---------------------------------------------------------------------------
// XA[t][n][j] = x[n,t,:] @ Wx.  16384 x 1024 x 4096, BK=64 dbuf, 2 blocks/CU.
// B16A=1: A staged via gll16 from pre-converted xb.  B16A=0: A reg-staged
// from fp32 x (inline convert).  XCD-chunked bid swizzle: each XCD owns 16
// A-slabs (L2-resident) and sweeps all 32 ntiles.
template <int B16A>
__global__ __launch_bounds__(256) void xa_gemm3(
    const float* __restrict__ x,        // [128][128][1024] fp32 (B16A=0)
    const ushort* __restrict__ xb,      // same, bf16 (B16A=1)
    const ushort* __restrict__ WxT,     // [4096][1024]
    ushort* __restrict__ xab)           // [128t][128n][4096]
{
    __shared__ ushort As[2][128 * 64];  // 16 KB each
    __shared__ ushort Bs[2][128 * 64];
    const int tid = threadIdx.x;
    const int w = tid >> 6, l = tid & 63;
    const int wm = w >> 1, wn = w & 1;
    const int lr = l & 15, g = l >> 4;

    const int bid = blockIdx.x;          // 4096 linear
    const int xcd = bid & 7, ii = bid >> 3;
    const int mt = xcd * 16 + (ii & 15); // A slab (= n), 16 per XCD
    const int n0 = (ii >> 4) * 128;      // ntile sweeps within XCD

    const float*  Ax  = x  + (size_t)mt * 128 * 1024;
    const ushort* Axb = xb + (size_t)mt * 128 * 1024;
    const ushort* Bb  = WxT + (size_t)n0 * 1024;

#define STAGEA(b, kf)                                                          \
    do {                                                                       \
        if (B16A) {                                                            \
            _Pragma("unroll")                                                  \
            for (int i = 0; i < 4; ++i) {                                      \
                int s = i * 256 + tid;                                         \
                int r = s >> 3, c = s & 7;                                     \
                gll16(Axb + (size_t)r * 1024 + (kf) + (c ^ (r & 7)) * 8,       \
                      &As[b][s * 8]);                                          \
            }                                                                  \
        } else {                                                               \
            _Pragma("unroll")                                                  \
            for (int i = 0; i < 4; ++i) {                                      \
                int u = i * 256 + tid;                                         \
                int r = u >> 3, c = u & 7;                                     \
                const float* s = Ax + (size_t)r * 1024 + (kf) + c * 8;         \
                float4 v0 = *(const float4*)s;                                 \
                float4 v1 = *(const float4*)(s + 4);                           \
                union { ushort us[8]; uint4 v; } o;                            \
                o.us[0]=f2b(v0.x); o.us[1]=f2b(v0.y); o.us[2]=f2b(v0.z);       \
                o.us[3]=f2b(v0.w); o.us[4]=f2b(v1.x); o.us[5]=f2b(v1.y);       \
                o.us[6]=f2b(v1.z); o.us[7]=f2b(v1.w);                          \
                *(uint4*)&As[b][(r * 8 + (c ^ (r & 7))) * 8] = o.v;            \
            }                                                                  \
        }                                                                      \
    } while (0)
#define STAGEB(b, kf)                                                          \
    do {                                                                       \
        _Pragma("unroll")                                                      \
        for (int s2 = 0; s2 < 4; ++s2) {                                       \
            int s = s2 * 256 + tid;                                            \
            int r = s >> 3, c = s & 7;                                         \
            gll16(Bb + (size_t)r * 1024 + (kf) + (c ^ (r & 7)) * 8,            \
                  &Bs[b][s * 8]);                                              \
        }                                                                      \
    } while (0)

    float4v acc[4][4];
#pragma unroll
    for (int i = 0; i < 4; ++i)
#pragma unroll
        for (int j = 0; j < 4; ++j) acc[i][j] = (float4v){0.f, 0.f, 0.f, 0.f};

    STAGEA(0, 0);
    STAGEB(0, 0);
    __syncthreads();
    int buf = 0;
#pragma unroll 1
    for (int kc = 0; kc < 16; ++kc) {
        if (kc < 15) { STAGEA(buf ^ 1, (kc + 1) * 64); STAGEB(buf ^ 1, (kc + 1) * 64); }
        const ushort* Ab = As[buf];
        const ushort* Bbuf = Bs[buf];
#pragma unroll
        for (int sub = 0; sub < 2; ++sub) {
            short8v af[4], bf[4];
#pragma unroll
            for (int mf = 0; mf < 4; ++mf) {
                int ra = wm * 64 + mf * 16 + lr;
                af[mf] = *(const short8v*)&Ab[ra * 64 + (((sub * 4 + g) ^ (ra & 7)) * 8)];
            }
#pragma unroll
            for (int nf = 0; nf < 4; ++nf) {
                int rb = wn * 64 + nf * 16 + lr;
                bf[nf] = *(const short8v*)&Bbuf[rb * 64 + (((sub * 4 + g) ^ (rb & 7)) * 8)];
            }
#pragma unroll
            for (int mf = 0; mf < 4; ++mf)
#pragma unroll
                for (int nf = 0; nf < 4; ++nf)
                    acc[mf][nf] = __builtin_amdgcn_mfma_f32_16x16x32_bf16(
                        af[mf], bf[nf], acc[mf][nf], 0, 0, 0);
        }
        __syncthreads();
        buf ^= 1;
    }
#undef STAGEA
#undef STAGEB

#pragma unroll
    for (int mf = 0; mf < 4; ++mf)
#pragma unroll
        for (int nf = 0; nf < 4; ++nf) {
            const int col = n0 + wn * 64 + nf * 16 + lr;
#pragma unroll
            for (int j = 0; j < 4; ++j) {
                const int rl = wm * 64 + mf * 16 + g * 4 + j;   // = t
                xab[((size_t)rl * NB + mt) * FH + col] = f2b(acc[mf][nf][j]);
            }
        }
}

// ---------------------------------------------------------------------------
// Per-step kernel. XAF=1: K=1024 (h @ WhT), XA added in epilogue, 4 K-iters.
// XAF=0: K=2048 ([x_t|h]), 8 K-iters fallback.
// 512 blocks (2/CU), 256 thr = 4 waves (2 mh x 2 kh); 32n x 32j per block.
template <int XAF>
__global__ __launch_bounds__(256) void step_kernel(
    const ushort* __restrict__ hcur,    // [128][1024] bf16
    ushort* __restrict__ hnext,
    const ushort* __restrict__ xb_t,    // XAF=0: + t*HD, row stride TT*HD
    const ushort* __restrict__ xab_t,   // XAF=1: + t*NB*FH
    const ushort* __restrict__ WxT,     // [4096][1024]
    const ushort* __restrict__ WhT,     // [4096][1024]
    const ushort* __restrict__ P2,      // [128][4096][16]
    const ushort* __restrict__ Ab16,    // [128][1024][16]
    const float* __restrict__ bias,
    float* __restrict__ cbuf,
    const float* __restrict__ qk_cur,   // [QB][2048]
    float* __restrict__ qk_next,
    float* __restrict__ qk_zero,
    float* __restrict__ out_t)          // + t*HD, row stride TT*HD
{
    __shared__ ushort AS[16384];
    __shared__ ushort BS[16384];
    __shared__ float accL[2 * 32 * 33];
    __shared__ float wLDS[32 * 16];

    const int tid = threadIdx.x;
    const int w = tid >> 6, l = tid & 63;
    const int mh = w & 1, kh = w >> 1;
    const int lr = l & 15, g = l >> 4;

    // XCD-chunked swizzle
    const int bid = blockIdx.x;
    const int xcd = bid & 7, ii = bid >> 3;
    const int bx = xcd * 16 + (ii & 15);
    const int my = ii >> 4;
    const int n0 = my * 32;

#define STAGE(b, kc)                                                           \
    do {                                                                       \
        _Pragma("unroll")                                                      \
        for (int i = 0; i < 4; ++i) {                                          \
            int u = i * 256 + tid;                                             \
            int skh = u >> 9, rem = u & 511;                                   \
            int r = rem >> 4, c = rem & 15;                                    \
            int lc = swz(c, r);                                                \
            const ushort* src;                                                 \
            if (XAF == 1)                                                      \
                src = hcur + (size_t)(n0 + r) * 1024 + skh * 512               \
                      + (kc) * 128 + lc * 8;                                   \
            else                                                               \
                src = skh                                                      \
                    ? hcur + (size_t)(n0 + r) * 1024 + (kc) * 128 + lc * 8     \
                    : xb_t + (size_t)(n0 + r) * (TT * HD) + (kc) * 128 + lc * 8;\
            gll16(src, AS + (((b) * 2 + skh) * 512 + rem) * 8);                \
        }                                                                      \
        _Pragma("unroll")                                                      \
        for (int i = 0; i < 4; ++i) {                                          \
            int u = i * 256 + tid;                                             \
            int skh = u >> 9, rem = u & 511;                                   \
            int r = rem >> 4, c = rem & 15;                                    \
            int lc = swz(c, r);                                                \
            int jg = (r >> 3) * 1024 + bx * 8 + (r & 7);                       \
            const ushort* src;                                                 \
            if (XAF == 1)                                                      \
                src = WhT + (size_t)jg * 1024 + skh * 512 + (kc) * 128 + lc * 8;\
            else                                                               \
                src = (skh ? WhT : WxT) + (size_t)jg * 1024                    \
                      + (kc) * 128 + lc * 8;                                   \
            gll16(src, BS + (((b) * 2 + skh) * 512 + rem) * 8);                \
        }                                                                      \
    } while (0)

    // issue first stage immediately; its HBM/L2 latency hides under the
    // qk-zero + softmax VALU work below.
    STAGE(0, 0);

    if (bid < 128) qk_zero[bid * 256 + tid] = 0.f;

    if (tid < 32) {   // softmax(qk/32): sum QB buckets, then exp-normalize
        const float* q = qk_cur + (n0 + tid) * 16;
        float4 s4[4];
#pragma unroll
        for (int q4 = 0; q4 < 4; ++q4) s4[q4] = ((const float4*)q)[q4];
#pragma unroll
        for (int bkt = 1; bkt < QB; ++bkt) {
            const float4* qb = (const float4*)(q + bkt * 2048);
#pragma unroll
            for (int q4 = 0; q4 < 4; ++q4) {
                float4 v = qb[q4];
                s4[q4].x += v.x; s4[q4].y += v.y; s4[q4].z += v.z; s4[q4].w += v.w;
            }
        }
        float s[16];
#pragma unroll
        for (int q4 = 0; q4 < 4; ++q4) {
            s[q4*4+0] = s4[q4].x; s[q4*4+1] = s4[q4].y;
            s[q4*4+2] = s4[q4].z; s[q4*4+3] = s4[q4].w;
        }
        float m = -1e30f;
#pragma unroll
        for (int k = 0; k < 16; ++k) { s[k] *= 0.03125f; m = fmaxf(m, s[k]); }
        float sum = 0.f;
#pragma unroll
        for (int k = 0; k < 16; ++k) { s[k] = __expf(s[k] - m); sum += s[k]; }
        float inv = __builtin_amdgcn_rcpf(sum);
#pragma unroll
        for (int k = 0; k < 16; ++k) wLDS[tid * 16 + k] = s[k] * inv;
    }

    float4v acc[2];
    acc[0] = (float4v){0.f, 0.f, 0.f, 0.f};
    acc[1] = (float4v){0.f, 0.f, 0.f, 0.f};

    const int NK = (XAF == 1) ? 4 : 8;
    __syncthreads();
    int buf = 0;
#pragma unroll 1
    for (int kc = 0; kc < NK; ++kc) {
        if (kc + 1 < NK) STAGE(buf ^ 1, kc + 1);
        const int base = (buf * 2 + kh) * 512;
        const int ra = mh * 16 + lr;
#pragma unroll
        for (int ks = 0; ks < 4; ++ks) {
            const int c = ks * 4 + g;
            short8v af = *(const short8v*)&AS[(base + ra * 16 + swz(c, ra)) * 8];
#pragma unroll
            for (int nf = 0; nf < 2; ++nf) {
                const int rb = nf * 16 + lr;
                short8v bf = *(const short8v*)&BS[(base + rb * 16 + swz(c, rb)) * 8];
                acc[nf] = __builtin_amdgcn_mfma_f32_16x16x32_bf16(af, bf, acc[nf], 0, 0, 0);
            }
        }
        __syncthreads();
        buf ^= 1;
    }
#undef STAGE

    // combine K-halves via LDS
#pragma unroll
    for (int nf = 0; nf < 2; ++nf)
#pragma unroll
        for (int jj = 0; jj < 4; ++jj)
            accL[(kh * 32 + mh * 16 + g * 4 + jj) * 33 + nf * 16 + lr] = acc[nf][jj];
    __syncthreads();

    // ---- epilogue: thread = one (n, hc) cell ----
    const int n_l = tid >> 3, hcl = tid & 7;
    const int n = n0 + n_l;
    const int hc = bx * 8 + hcl;

    float wv_[16];
#pragma unroll
    for (int k = 0; k < 16; ++k) wv_[k] = wLDS[n_l * 16 + k];

    float val[4];
#pragma unroll
    for (int q = 0; q < 4; ++q) {
        const int cq = q * 8 + hcl;
        float v = accL[n_l * 33 + cq] + accL[(32 + n_l) * 33 + cq]
                + bias[q * 1024 + hc];
        if (XAF == 1) v += b2f(xab_t[(size_t)n * FH + q * 1024 + hc]);
        const ushort* pp = P2 + ((size_t)n * FH + q * 1024 + hc) * 16;
        union { uint4 v[2]; ushort us[16]; } pv;
        pv.v[0] = *(const uint4*)pp;
        pv.v[1] = *(const uint4*)(pp + 8);
#pragma unroll
        for (int k = 0; k < 16; ++k) v += wv_[k] * b2f(pv.us[k]);
        val[q] = v;
    }

    const size_t chidx = (size_t)n * 1024 + hc;
    float cn = sigm(val[1]) * cbuf[chidx] + sigm(val[0]) * tanh_fast(val[3]);
    float hv = sigm(val[2]) * tanh_fast(cn);
    cbuf[chidx] = cn;
    out_t[(size_t)n * (TT * HD) + hc] = hv;
    hnext[chidx] = f2b(hv);

    // qk partials: p[k] = hv * A[n][hc][k], reduced over 8 hcl lanes
    union { uint4 v[2]; ushort us[16]; } av;
    {
        const ushort* ap = Ab16 + chidx * 16;
        av.v[0] = *(const uint4*)ap;
        av.v[1] = *(const uint4*)(ap + 8);
    }
    float vv[16];
#pragma unroll
    for (int k = 0; k < 16; ++k) vv[k] = hv * b2f(av.us[k]);
    {
        bool hi = (hcl & 1);
#pragma unroll
        for (int q = 0; q < 8; ++q) {
            float send = hi ? vv[q] : vv[q + 8];
            float recv = __shfl_xor(send, 1);
            vv[q] = (hi ? vv[q + 8] : vv[q]) + recv;
        }
        hi = (hcl & 2);
#pragma unroll
        for (int q = 0; q < 4; ++q) {
            float send = hi ? vv[q] : vv[q + 4];
            float recv = __shfl_xor(send, 2);
            vv[q] = (hi ? vv[q + 4] : vv[q]) + recv;
        }
        hi = (hcl & 4);
#pragma unroll
        for (int q = 0; q < 2; ++q) {
            float send = hi ? vv[q] : vv[q + 2];
            float recv = __shfl_xor(send, 4);
            vv[q] = (hi ? vv[q + 2] : vv[q]) + recv;
        }
    }
    const int kbase = ((hcl & 1) << 3) | ((hcl & 2) << 1) | ((hcl & 4) >> 1);
    float* qdst = qk_next + (bx & (QB - 1)) * 2048 + n * 16;
    atomicAdd(qdst + kbase,     vv[0]);
    atomicAdd(qdst + kbase + 1, vv[1]);
}

// ---------------------------------------------------------------------------
extern "C" void kernel_launch(void* const* d_in, const int* in_sizes, int n_in,
                              void* d_out, int out_size, void* d_ws, size_t ws_size,
                              hipStream_t stream) {
    const float* x     = (const float*)d_in[0];
    const float* A     = (const float*)d_in[1];
    const float* Wx    = (const float*)d_in[2];
    const float* Wh    = (const float*)d_in[3];
    const float* Wattn = (const float*)d_in[4];
    const float* b     = (const float*)d_in[5];
    float* out = (float*)d_out;

    ushort* WT   = (ushort*)d_ws;                          // 3 x 8.39 MB
    ushort* WxT  = WT;
    ushort* WhT  = WT + (size_t)FH * 1024;
    ushort* WatT = WT + (size_t)2 * FH * 1024;
    ushort* Ab16 = WT + (size_t)3 * FH * 1024;             // 4.19 MB
    ushort* hb   = Ab16 + (size_t)NB * HD * 16;            // 2 x 0.26 MB
    float*  cb   = (float*)(hb + (size_t)2 * NB * HD);     // 0.52 MB
    float*  qk   = cb + (size_t)NB * HD;                   // 3 x 128 KB
    ushort* P2   = (ushort*)(qk + 3 * QSLOT);              // 16.78 MB
    ushort* tail = P2 + (size_t)NB * FH * 16;

    const size_t base  = (size_t)((char*)tail - (char*)d_ws);
    const size_t xasz  = (size_t)TT * NB * FH * 2;         // 134.2 MB
    const size_t xbsz  = (size_t)NB * TT * HD * 2;         // 33.55 MB

    build_wt<<<dim3(48, 64), 256, 0, stream>>>(Wx, Wh, Wattn, WT);
    init_kernel<<<NB, 256, 0, stream>>>(A, cb, hb, Ab16, qk, qk + QSLOT);
    p_gemm<<<dim3(16, 32), 256, 0, stream>>>(Ab16, WatT, P2);

    if (ws_size >= base + xasz) {
        ushort* xab = tail;
        if (ws_size >= base + xasz + xbsz) {
            // bf16-A path: pre-convert x, gll16 both operands
            ushort* xb = tail + xasz / 2;
            cvt_x<<<8192, 256, 0, stream>>>(x, xb);
            xa_gemm3<1><<<4096, 256, 0, stream>>>(nullptr, xb, WxT, xab);
        } else {
            xa_gemm3<0><<<4096, 256, 0, stream>>>(x, nullptr, WxT, xab);
        }
        for (int t = 0; t < TT; ++t) {
            const ushort* hc = hb + (size_t)(t & 1) * NB * HD;
            ushort* hn       = hb + (size_t)((t + 1) & 1) * NB * HD;
            const float* qc  = qk + (size_t)(t % 3) * QSLOT;
            float* qn        = qk + (size_t)((t + 1) % 3) * QSLOT;
            float* qz        = qk + (size_t)((t + 2) % 3) * QSLOT;
            step_kernel<1><<<512, 256, 0, stream>>>(
                hc, hn, nullptr, xab + (size_t)t * NB * FH, WxT, WhT, P2, Ab16,
                b, cb, qc, qn, qz, out + (size_t)t * HD);
        }
    } else {
        ushort* xb = tail;
        cvt_x<<<8192, 256, 0, stream>>>(x, xb);
        for (int t = 0; t < TT; ++t) {
            const ushort* hc = hb + (size_t)(t & 1) * NB * HD;
            ushort* hn       = hb + (size_t)((t + 1) & 1) * NB * HD;
            const float* qc  = qk + (size_t)(t % 3) * QSLOT;
            float* qn        = qk + (size_t)((t + 1) % 3) * QSLOT;
            float* qz        = qk + (size_t)((t + 2) % 3) * QSLOT;
            step_kernel<0><<<512, 256, 0, stream>>>(
                hc, hn, xb + (size_t)t * HD, nullptr, WxT, WhT, P2, Ab16,
                b, cb, qc, qn, qz, out + (size_t)t * HD);
        }
    }
}